// Round 7
// baseline (273.590 us; speedup 1.0000x reference)
//
#include <hip/hip_runtime.h>
#include <stdint.h>

typedef unsigned short u16;
typedef __attribute__((ext_vector_type(8))) short short8;
typedef __attribute__((ext_vector_type(4))) short short4v;
typedef __attribute__((ext_vector_type(4))) float f32x4;

#define LOG2E 1.44269504088896340736f

#define Bb 8
#define NSEQ 1024
#define DIMC 768
#define NH 12
#define DH 64
#define INNER 768
#define MTOT (Bb*NSEQ)      /* 8192 */
#define QKVN (3*INNER)      /* 2304 */
#define HEADS_TOT (Bb*NH)   /* 96 */
#define QKV_PART ((size_t)Bb*NH*NSEQ*DH)

static __device__ inline u16 f2bf(float f) {
    uint32_t u = __builtin_bit_cast(uint32_t, f);
    uint32_t r = (u + 0x7fffu + ((u >> 16) & 1u)) >> 16;
    return (u16)r;
}

// pack two f32 -> bf16 pair (round-half-up) in 3 VALU ops via v_perm
static __device__ __forceinline__ uint32_t pkbf(float f0, float f1) {
    uint32_t u0 = __builtin_bit_cast(uint32_t, f0) + 0x8000u;
    uint32_t u1 = __builtin_bit_cast(uint32_t, f1) + 0x8000u;
    return __builtin_amdgcn_perm(u1, u0, 0x07060302u);
}

// 16x16x16 bf16 MFMA: B-operand k-packing matches 16x16 MFMA C-layout
#if __has_builtin(__builtin_amdgcn_mfma_f32_16x16x16bf16_1k)
static __device__ __forceinline__ f32x4 mfma16(short4v a, short4v b, f32x4 c) {
    return __builtin_amdgcn_mfma_f32_16x16x16bf16_1k(a, b, c, 0, 0, 0);
}
#else
static __device__ __forceinline__ f32x4 mfma16(short4v a, short4v b, f32x4 c) {
    asm volatile("v_mfma_f32_16x16x16_bf16 %0, %1, %2, %0\n\ts_nop 7\n\ts_nop 7"
                 : "+v"(c) : "v"(a), "v"(b));
    return c;
}
#endif

// ---- async global->LDS, 16B per lane; keeps staged data OUT of the VGPR file ----
typedef __attribute__((address_space(1))) const void gas_void;
typedef __attribute__((address_space(3))) void las_void;
static __device__ __forceinline__ void async16(u16* lds, const u16* g) {
    __builtin_amdgcn_global_load_lds((gas_void*)(uintptr_t)g,
                                     (las_void*)(uintptr_t)lds, 16, 0, 0);
}

// counted vmcnt wait: N = my loads allowed to remain in flight.
// gfx9 vmcnt is 6 bits: [3:0] at simm[3:0], [5:4] at simm[15:14].
template <int N>
static __device__ __forceinline__ void wait_vm() {
    constexpr int simm = 0x0f70 | (N & 15) | ((N >> 4) << 14);
    __builtin_amdgcn_s_waitcnt(simm);
}

// NOTE (round-5 lesson, hard-measured): s_setprio around the MFMA cluster in these
// lockstep barrier loops is TOXIC (qkv 46.6 -> 62.8 us, WRITE_SIZE 40 -> 63 MB).
// T5 requires a phase-split schedule to arbitrate; do not re-add it to these loops.

// ---------------- fused fp32 -> bf16 conversion (single dispatch) ----------------
#define NX8  786432
#define NWQ8 221184
#define NWP8 73728
#define NCVT (NX8 + NWQ8 + NWP8)
__global__ __launch_bounds__(256) void cvt_all(const float* __restrict__ x,
                                               const float* __restrict__ wq,
                                               const float* __restrict__ wp,
                                               u16* __restrict__ xb,
                                               u16* __restrict__ wqb,
                                               u16* __restrict__ wpb) {
    int i = blockIdx.x * 256 + threadIdx.x;
    const float* s; u16* d; int j;
    if (i < NX8) { s = x; d = xb; j = i; }
    else if (i < NX8 + NWQ8) { s = wq; d = wqb; j = i - NX8; }
    else { s = wp; d = wpb; j = i - NX8 - NWQ8; }
    const float4* s4 = (const float4*)s;
    float4 a = s4[2 * j], b = s4[2 * j + 1];
    float v[8] = {a.x, a.y, a.z, a.w, b.x, b.y, b.z, b.w};
    u16 o[8];
#pragma unroll
    for (int t = 0; t < 8; t++) o[t] = f2bf(v[t]);
    ((uint4*)d)[j] = *(const uint4*)o;
}

// ---------------- QKV GEMM: round-1 verbatim (best measured: 45.7-46.6 us) --------
// 512 thr, 128x256, BK=32, 3-buffer counted-vmcnt pipeline. Raw s_barrier, no
// sched_barrier, no setprio (round-5 proved setprio regresses this loop 35%).
#define BK 32
__global__ __launch_bounds__(512, 4) void gemm_qkv(const u16* __restrict__ A,
                                                   const u16* __restrict__ Bm,
                                                   u16* __restrict__ qkv) {
    __shared__ u16 As[3][128 * BK];   // 3 x 8 KB
    __shared__ u16 Bs[3][256 * BK];   // 3 x 16 KB  (72 KB total -> 2 blocks/CU)
    const int tid = threadIdx.x;
    const int w = tid >> 6, lane = tid & 63, quad = lane >> 4, l16 = lane & 15;
    const int wr = w >> 2, wc = w & 3;           // 2 x 4 wave grid, 64x64 each
    const int bid = blockIdx.x + 9 * blockIdx.y; // 0..575
    const int xcd = bid & 7, j9 = bid >> 3;      // j9 in 0..71
    const int m0 = (8 * xcd + j9 / 9) * 128;     // 8 consecutive m-panels per XCD
    const int n0 = (j9 % 9) * 256;
    const int K = DIMC;

    const int rl = lane >> 2, cc = lane & 3;
    const int ra = w * 16 + rl;
    const u16* agp = A + (size_t)(m0 + ra) * K + ((cc - ((ra >> 1) & 3)) & 3) * 8;
    const int aslot = (w * 16) * BK;
    const u16* bgp[2]; int bslot[2];
#pragma unroll
    for (int j = 0; j < 2; j++) {
        int rb = w * 32 + j * 16 + rl;
        bgp[j] = Bm + (size_t)(n0 + rb) * K + ((cc - ((rb >> 1) & 3)) & 3) * 8;
        bslot[j] = (w * 32 + j * 16) * BK;
    }

    const int swz = ((quad + ((l16 >> 1) & 3)) & 3) * 8;
    int aoff[4], boff[4];
#pragma unroll
    for (int t = 0; t < 4; t++) {
        aoff[t] = (wr * 64 + t * 16 + l16) * BK + swz;
        boff[t] = (wc * 64 + t * 16 + l16) * BK + swz;
    }

    // prefetch tiles 0 and 1
#pragma unroll
    for (int tt = 0; tt < 2; tt++) {
        int kt = tt * BK;
        async16(&As[tt][aslot], agp + kt);
        async16(&Bs[tt][bslot[0]], bgp[0] + kt);
        async16(&Bs[tt][bslot[1]], bgp[1] + kt);
    }

    f32x4 acc[4][4] = {};
    const int NIT = K / BK;   // 24
    int cur = 0;
    for (int it = 0; it < NIT; ++it) {
        if (it < NIT - 1) wait_vm<3>();   // tile it landed; tile it+1 stays in flight
        else              wait_vm<0>();
        __builtin_amdgcn_s_barrier();
        if (it < NIT - 2) {
            int pre = cur + 2; if (pre >= 3) pre -= 3;
            int ktn = (it + 2) * BK;
            async16(&As[pre][aslot], agp + ktn);
            async16(&Bs[pre][bslot[0]], bgp[0] + ktn);
            async16(&Bs[pre][bslot[1]], bgp[1] + ktn);
        }
        short8 af[4], bf[4];
#pragma unroll
        for (int t = 0; t < 4; t++) af[t] = *(const short8*)(&As[cur][aoff[t]]);
#pragma unroll
        for (int t = 0; t < 4; t++) bf[t] = *(const short8*)(&Bs[cur][boff[t]]);
#pragma unroll
        for (int mt = 0; mt < 4; mt++)
#pragma unroll
            for (int nt = 0; nt < 4; nt++)
                acc[mt][nt] = __builtin_amdgcn_mfma_f32_16x16x32_bf16(af[mt], bf[nt],
                                                                      acc[mt][nt], 0, 0, 0);
        cur = (cur == 2) ? 0 : cur + 1;
    }

#pragma unroll
    for (int nt = 0; nt < 4; nt++) {
        int o = n0 + wc * 64 + nt * 16 + l16;
        int which = o / 768;
        int rem = o - which * 768;
        int h = rem >> 6, d = rem & 63;
        if (which == 2) {
            u16* vt = qkv + 2 * QKV_PART;
#pragma unroll
            for (int mt = 0; mt < 4; mt++) {
                int m = m0 + wr * 64 + mt * 16 + quad * 4;
                int bb = m >> 10, ns = m & 1023;
                alignas(8) u16 pk[4];
#pragma unroll
                for (int r = 0; r < 4; r++) pk[r] = f2bf(acc[mt][nt][r]);
                *(uint2*)(vt + ((size_t)(bb * NH + h) * DH + d) * NSEQ + ns) =
                    *(const uint2*)pk;
            }
        } else {
            float sc = (which == 0) ? (0.125f * LOG2E) : 1.0f;
#pragma unroll
            for (int mt = 0; mt < 4; mt++)
#pragma unroll
                for (int r = 0; r < 4; r++) {
                    int m = m0 + wr * 64 + mt * 16 + quad * 4 + r;
                    int bb = m >> 10, ns = m & 1023;
                    size_t idx = (size_t)which * QKV_PART +
                                 (((size_t)(bb * NH + h) * NSEQ + ns) << 6) + d;
                    qkv[idx] = f2bf(acc[mt][nt][r] * sc);
                }
        }
    }
}

// ---------------- proj GEMM: round-4 verbatim (best measured proj) ----------------
// m97-style: 256 thr, 64x128, BK=32, single 12KB buffer, lb(256,4), grid 768=3/CU.
#define PBM 64
#define PBN 128
__global__ __launch_bounds__(256, 4) void gemm_proj(const u16* __restrict__ A,
                                                    const u16* __restrict__ Bm,
                                                    float* __restrict__ Co) {
    __shared__ u16 As[PBM * BK];   // 4 KB
    __shared__ u16 Bs[PBN * BK];   // 8 KB
    const int tid = threadIdx.x;
    const int w = tid >> 6, lane = tid & 63, quad = lane >> 4, l16 = lane & 15;
    const int wr = w >> 1, wc = w & 1;   // 2 x 2 wave grid, each 32x64
    const int m0 = blockIdx.y * PBM;
    const int n0 = blockIdx.x * PBN;
    const int K = INNER, N = DIMC;

    const int rl = lane >> 2, cc = lane & 3;
    const int ra = w * 16 + rl;
    const u16* agp = A + (size_t)(m0 + ra) * K + ((cc - ((ra >> 1) & 3)) & 3) * 8;
    const int aslot = (w * 16) * BK;
    const u16* bgp[2]; int bslot[2];
#pragma unroll
    for (int j = 0; j < 2; j++) {
        int rb = j * 64 + w * 16 + rl;
        bgp[j] = Bm + (size_t)(n0 + rb) * K + ((cc - ((rb >> 1) & 3)) & 3) * 8;
        bslot[j] = (j * 64 + w * 16) * BK;
    }
    const int swz = ((quad + ((l16 >> 1) & 3)) & 3) * 8;
    int aoff[2], boff[4];
#pragma unroll
    for (int t = 0; t < 2; t++) aoff[t] = (wr * 32 + t * 16 + l16) * BK + swz;
#pragma unroll
    for (int t = 0; t < 4; t++) boff[t] = (wc * 64 + t * 16 + l16) * BK + swz;

    f32x4 acc[2][4] = {};
    const int NIT = K / BK;   // 24
    for (int it = 0; it < NIT; ++it) {
        int kt = it * BK;
        async16(&As[aslot], agp + kt);
        async16(&Bs[bslot[0]], bgp[0] + kt);
        async16(&Bs[bslot[1]], bgp[1] + kt);
        __syncthreads();
        short8 af[2], bf[4];
#pragma unroll
        for (int t = 0; t < 2; t++) af[t] = *(const short8*)(&As[aoff[t]]);
#pragma unroll
        for (int t = 0; t < 4; t++) bf[t] = *(const short8*)(&Bs[boff[t]]);
#pragma unroll
        for (int mt = 0; mt < 2; mt++)
#pragma unroll
            for (int nt = 0; nt < 4; nt++)
                acc[mt][nt] = __builtin_amdgcn_mfma_f32_16x16x32_bf16(af[mt], bf[nt],
                                                                      acc[mt][nt], 0, 0, 0);
        __syncthreads();
    }
#pragma unroll
    for (int mt = 0; mt < 2; mt++)
#pragma unroll
        for (int nt = 0; nt < 4; nt++) {
            int o = n0 + wc * 64 + nt * 16 + l16;
#pragma unroll
            for (int r = 0; r < 4; r++) {
                int m = m0 + wr * 32 + mt * 16 + quad * 4 + r;
                Co[(size_t)m * N + o] = acc[mt][nt][r];
            }
        }
}

// ---------------- Flash attention: LDS-FREE direct-global K/V (round-7) -----------
// Guide m168->m169 precedent (same S=1024, K/V=256KB/head, L2-fits): staging K/V
// through LDS is pure overhead. Grid (96,8): same head's 8 q-tiles differ by 96
// blocks == 0 mod 8 -> same XCD; per-XCD K/V set = 12 heads x 256KB = 3MB < 4MB L2.
// So K/V fragments are read directly from global (L2-hit after first touch):
//   kf[nt][j] = K[(kt+nt*16+l16)*64 + j*32 + quad*8]        (16B, aligned)
//   vf[nt2][c] = V^T[(nt2*16+l16)*1024 + kt + c*16 + quad*4] (8B, aligned)
// — verified identical operands to the old staged path (LDS chunk-rotation inverts
// to these addresses). No LDS, no barriers, no vmcnt: every wave independent; also
// kills the 1.57M LDS bank conflicts measured on the old V-read pattern (R2).
__global__ __launch_bounds__(256) void attn_kernel(const u16* __restrict__ qkv,
                                                   u16* __restrict__ attn) {
    const int tid = threadIdx.x;
    const int w = tid >> 6, lane = tid & 63, quad = lane >> 4, l16 = lane & 15;
    const int bh = blockIdx.x, qt = blockIdx.y;
    const size_t headoff = (size_t)bh * NSEQ * DH;
    const u16* Qp = qkv + headoff;
    const u16* Kp = qkv + QKV_PART + headoff;
    const u16* Vtp = qkv + 2 * QKV_PART + headoff;
    const int q0 = qt * 128 + w * 32;

    short8 qf[2][2];
#pragma unroll
    for (int mf = 0; mf < 2; mf++) {
        qf[mf][0] = *(const short8*)(Qp + (size_t)(q0 + mf * 16 + l16) * DH + quad * 8);
        qf[mf][1] = *(const short8*)(Qp + (size_t)(q0 + mf * 16 + l16) * DH + 32 + quad * 8);
    }

    f32x4 oacc[2][4] = {};          // O^T[d][q]
    float lsum[2] = {0.f, 0.f};

    const int NIT = NSEQ / 64;   // 16
    for (int it = 0; it < NIT; ++it) {
        const int kt = it * 64;

        // K fragments: rows = key positions kt..kt+63, 16B per lane, L2-hit
        short8 kf[4][2];
#pragma unroll
        for (int nt = 0; nt < 4; nt++) {
            const u16* kr = Kp + (size_t)(kt + nt * 16 + l16) * DH + quad * 8;
            kf[nt][0] = *(const short8*)(kr);
            kf[nt][1] = *(const short8*)(kr + 32);
        }
        // V^T fragments: rows = d, cols = key positions, 8B per lane, L2-hit
        short4v vf[4][4];
#pragma unroll
        for (int nt2 = 0; nt2 < 4; nt2++) {
            const u16* vr = Vtp + (size_t)(nt2 * 16 + l16) * NSEQ + kt + quad * 4;
#pragma unroll
            for (int c = 0; c < 4; c++)
                vf[nt2][c] = *(const short4v*)(vr + c * 16);
        }

#pragma unroll
        for (int mf = 0; mf < 2; mf++) {
            f32x4 st[4];
#pragma unroll
            for (int nt = 0; nt < 4; nt++) {
                f32x4 z = {};
                z = __builtin_amdgcn_mfma_f32_16x16x32_bf16(kf[nt][0], qf[mf][0], z, 0, 0, 0);
                z = __builtin_amdgcn_mfma_f32_16x16x32_bf16(kf[nt][1], qf[mf][1], z, 0, 0, 0);
                st[nt] = z;
            }
            short4v pf[4];
#pragma unroll
            for (int c = 0; c < 4; c++) {
                float p0 = __builtin_amdgcn_exp2f(st[c][0]);
                float p1 = __builtin_amdgcn_exp2f(st[c][1]);
                float p2 = __builtin_amdgcn_exp2f(st[c][2]);
                float p3 = __builtin_amdgcn_exp2f(st[c][3]);
                lsum[mf] += (p0 + p1) + (p2 + p3);
                uint2 u = {pkbf(p0, p1), pkbf(p2, p3)};
                pf[c] = __builtin_bit_cast(short4v, u);
            }
#pragma unroll
            for (int nt2 = 0; nt2 < 4; nt2++)
#pragma unroll
                for (int c = 0; c < 4; c++)
                    oacc[mf][nt2] = mfma16(vf[nt2][c], pf[c], oacc[mf][nt2]);
        }
    }

#pragma unroll
    for (int mf = 0; mf < 2; mf++) {
        float v = lsum[mf];
        v += __shfl_xor(v, 16);
        v += __shfl_xor(v, 32);
        lsum[mf] = 1.0f / v;
    }

    const int b = bh / NH, h = bh - (bh / NH) * NH;
#pragma unroll
    for (int mf = 0; mf < 2; mf++) {
        int q = q0 + mf * 16 + l16;
        float inv = lsum[mf];
#pragma unroll
        for (int nt2 = 0; nt2 < 4; nt2++) {
            uint2 u = {pkbf(oacc[mf][nt2][0] * inv, oacc[mf][nt2][1] * inv),
                       pkbf(oacc[mf][nt2][2] * inv, oacc[mf][nt2][3] * inv)};
            int d = nt2 * 16 + quad * 4;
            *(uint2*)(attn + ((size_t)(b * NSEQ + q)) * INNER + h * DH + d) = u;
        }
    }
}

extern "C" void kernel_launch(void* const* d_in, const int* in_sizes, int n_in,
                              void* d_out, int out_size, void* d_ws, size_t ws_size,
                              hipStream_t stream) {
    const float* x = (const float*)d_in[0];
    const float* w_qkv = (const float*)d_in[1];
    const float* w_proj = (const float*)d_in[2];
    float* out = (float*)d_out;

    u16* xb = (u16*)d_ws;
    u16* wqkvb = xb + 6291456;
    u16* wprojb = wqkvb + 1769472;
    u16* qkvb = wprojb + 589824;
    u16* attnb = qkvb + 18874368;

    cvt_all<<<NCVT / 256, 256, 0, stream>>>(x, w_qkv, w_proj, xb, wqkvb, wprojb);

    dim3 g1(QKVN / 256, MTOT / 128);   // (9, 64), 512 threads
    gemm_qkv<<<g1, 512, 0, stream>>>(xb, wqkvb, qkvb);

    dim3 g2(HEADS_TOT, NSEQ / 128);    // (96, 8) — same-head blocks co-XCD
    attn_kernel<<<g2, 256, 0, stream>>>(qkvb, attnb);

    dim3 g3(INNER / PBN, MTOT / PBM);  // (6, 128), 3 blocks/CU exact
    gemm_proj<<<g3, 256, 0, stream>>>(attnb, wprojb, out);
}

// Round 8
// 183.551 us; speedup vs baseline: 1.4905x; 1.4905x over previous
//
#include <hip/hip_runtime.h>
#include <stdint.h>

typedef unsigned short u16;
typedef __attribute__((ext_vector_type(8))) short short8;
typedef __attribute__((ext_vector_type(4))) short short4v;
typedef __attribute__((ext_vector_type(4))) float f32x4;

#define LOG2E 1.44269504088896340736f

#define Bb 8
#define NSEQ 1024
#define DIMC 768
#define NH 12
#define DH 64
#define INNER 768
#define MTOT (Bb*NSEQ)      /* 8192 */
#define QKVN (3*INNER)      /* 2304 */
#define HEADS_TOT (Bb*NH)   /* 96 */
#define QKV_PART ((size_t)Bb*NH*NSEQ*DH)

static __device__ inline u16 f2bf(float f) {
    uint32_t u = __builtin_bit_cast(uint32_t, f);
    uint32_t r = (u + 0x7fffu + ((u >> 16) & 1u)) >> 16;
    return (u16)r;
}

// pack two f32 -> bf16 pair (round-half-up) in 3 VALU ops via v_perm
static __device__ __forceinline__ uint32_t pkbf(float f0, float f1) {
    uint32_t u0 = __builtin_bit_cast(uint32_t, f0) + 0x8000u;
    uint32_t u1 = __builtin_bit_cast(uint32_t, f1) + 0x8000u;
    return __builtin_amdgcn_perm(u1, u0, 0x07060302u);
}

// 16x16x16 bf16 MFMA: B-operand k-packing matches 16x16 MFMA C-layout
#if __has_builtin(__builtin_amdgcn_mfma_f32_16x16x16bf16_1k)
static __device__ __forceinline__ f32x4 mfma16(short4v a, short4v b, f32x4 c) {
    return __builtin_amdgcn_mfma_f32_16x16x16bf16_1k(a, b, c, 0, 0, 0);
}
#else
static __device__ __forceinline__ f32x4 mfma16(short4v a, short4v b, f32x4 c) {
    asm volatile("v_mfma_f32_16x16x16_bf16 %0, %1, %2, %0\n\ts_nop 7\n\ts_nop 7"
                 : "+v"(c) : "v"(a), "v"(b));
    return c;
}
#endif

// ---- async global->LDS, 16B per lane; keeps staged data OUT of the VGPR file ----
typedef __attribute__((address_space(1))) const void gas_void;
typedef __attribute__((address_space(3))) void las_void;
static __device__ __forceinline__ void async16(u16* lds, const u16* g) {
    __builtin_amdgcn_global_load_lds((gas_void*)(uintptr_t)g,
                                     (las_void*)(uintptr_t)lds, 16, 0, 0);
}

// counted vmcnt wait: N = my loads allowed to remain in flight.
// gfx9 vmcnt is 6 bits: [3:0] at simm[3:0], [5:4] at simm[15:14].
template <int N>
static __device__ __forceinline__ void wait_vm() {
    constexpr int simm = 0x0f70 | (N & 15) | ((N >> 4) << 14);
    __builtin_amdgcn_s_waitcnt(simm);
}

static __device__ __forceinline__ void block_barrier() {
    __builtin_amdgcn_s_barrier();
    __builtin_amdgcn_sched_barrier(0);
}

// SESSION LEDGER (hard-measured, do not re-try):
//  - s_setprio in these lockstep loops: TOXIC (R5: qkv 46.6 -> 62.8 us).
//  - attn LDS-free direct-global K/V: TOXIC (R7: attn ~44 -> 139 us; L2-resident
//    but latency-bound serial load->MFMA chain, no compiler pipelining at 2.3
//    blocks/CU). Staged async16 + counted vmcnt is the required structure.
//  - qkv alternates (fat-wave, reg-dbuf, m97-small-tile): all <= round-1 form.

// ---------------- fused fp32 -> bf16 conversion (single dispatch) ----------------
#define NX8  786432
#define NWQ8 221184
#define NWP8 73728
#define NCVT (NX8 + NWQ8 + NWP8)
__global__ __launch_bounds__(256) void cvt_all(const float* __restrict__ x,
                                               const float* __restrict__ wq,
                                               const float* __restrict__ wp,
                                               u16* __restrict__ xb,
                                               u16* __restrict__ wqb,
                                               u16* __restrict__ wpb) {
    int i = blockIdx.x * 256 + threadIdx.x;
    const float* s; u16* d; int j;
    if (i < NX8) { s = x; d = xb; j = i; }
    else if (i < NX8 + NWQ8) { s = wq; d = wqb; j = i - NX8; }
    else { s = wp; d = wpb; j = i - NX8 - NWQ8; }
    const float4* s4 = (const float4*)s;
    float4 a = s4[2 * j], b = s4[2 * j + 1];
    float v[8] = {a.x, a.y, a.z, a.w, b.x, b.y, b.z, b.w};
    u16 o[8];
#pragma unroll
    for (int t = 0; t < 8; t++) o[t] = f2bf(v[t]);
    ((uint4*)d)[j] = *(const uint4*)o;
}

// ---------------- QKV GEMM: round-1 verbatim (best measured: 45.7-46.6 us) --------
// 512 thr, 128x256, BK=32, 3-buffer counted-vmcnt pipeline. Raw s_barrier, no
// sched_barrier, no setprio.
#define BK 32
__global__ __launch_bounds__(512, 4) void gemm_qkv(const u16* __restrict__ A,
                                                   const u16* __restrict__ Bm,
                                                   u16* __restrict__ qkv) {
    __shared__ u16 As[3][128 * BK];   // 3 x 8 KB
    __shared__ u16 Bs[3][256 * BK];   // 3 x 16 KB  (72 KB total -> 2 blocks/CU)
    const int tid = threadIdx.x;
    const int w = tid >> 6, lane = tid & 63, quad = lane >> 4, l16 = lane & 15;
    const int wr = w >> 2, wc = w & 3;           // 2 x 4 wave grid, 64x64 each
    const int bid = blockIdx.x + 9 * blockIdx.y; // 0..575
    const int xcd = bid & 7, j9 = bid >> 3;      // j9 in 0..71
    const int m0 = (8 * xcd + j9 / 9) * 128;     // 8 consecutive m-panels per XCD
    const int n0 = (j9 % 9) * 256;
    const int K = DIMC;

    const int rl = lane >> 2, cc = lane & 3;
    const int ra = w * 16 + rl;
    const u16* agp = A + (size_t)(m0 + ra) * K + ((cc - ((ra >> 1) & 3)) & 3) * 8;
    const int aslot = (w * 16) * BK;
    const u16* bgp[2]; int bslot[2];
#pragma unroll
    for (int j = 0; j < 2; j++) {
        int rb = w * 32 + j * 16 + rl;
        bgp[j] = Bm + (size_t)(n0 + rb) * K + ((cc - ((rb >> 1) & 3)) & 3) * 8;
        bslot[j] = (w * 32 + j * 16) * BK;
    }

    const int swz = ((quad + ((l16 >> 1) & 3)) & 3) * 8;
    int aoff[4], boff[4];
#pragma unroll
    for (int t = 0; t < 4; t++) {
        aoff[t] = (wr * 64 + t * 16 + l16) * BK + swz;
        boff[t] = (wc * 64 + t * 16 + l16) * BK + swz;
    }

    // prefetch tiles 0 and 1
#pragma unroll
    for (int tt = 0; tt < 2; tt++) {
        int kt = tt * BK;
        async16(&As[tt][aslot], agp + kt);
        async16(&Bs[tt][bslot[0]], bgp[0] + kt);
        async16(&Bs[tt][bslot[1]], bgp[1] + kt);
    }

    f32x4 acc[4][4] = {};
    const int NIT = K / BK;   // 24
    int cur = 0;
    for (int it = 0; it < NIT; ++it) {
        if (it < NIT - 1) wait_vm<3>();   // tile it landed; tile it+1 stays in flight
        else              wait_vm<0>();
        __builtin_amdgcn_s_barrier();
        if (it < NIT - 2) {
            int pre = cur + 2; if (pre >= 3) pre -= 3;
            int ktn = (it + 2) * BK;
            async16(&As[pre][aslot], agp + ktn);
            async16(&Bs[pre][bslot[0]], bgp[0] + ktn);
            async16(&Bs[pre][bslot[1]], bgp[1] + ktn);
        }
        short8 af[4], bf[4];
#pragma unroll
        for (int t = 0; t < 4; t++) af[t] = *(const short8*)(&As[cur][aoff[t]]);
#pragma unroll
        for (int t = 0; t < 4; t++) bf[t] = *(const short8*)(&Bs[cur][boff[t]]);
#pragma unroll
        for (int mt = 0; mt < 4; mt++)
#pragma unroll
            for (int nt = 0; nt < 4; nt++)
                acc[mt][nt] = __builtin_amdgcn_mfma_f32_16x16x32_bf16(af[mt], bf[nt],
                                                                      acc[mt][nt], 0, 0, 0);
        cur = (cur == 2) ? 0 : cur + 1;
    }

#pragma unroll
    for (int nt = 0; nt < 4; nt++) {
        int o = n0 + wc * 64 + nt * 16 + l16;
        int which = o / 768;
        int rem = o - which * 768;
        int h = rem >> 6, d = rem & 63;
        if (which == 2) {
            u16* vt = qkv + 2 * QKV_PART;
#pragma unroll
            for (int mt = 0; mt < 4; mt++) {
                int m = m0 + wr * 64 + mt * 16 + quad * 4;
                int bb = m >> 10, ns = m & 1023;
                alignas(8) u16 pk[4];
#pragma unroll
                for (int r = 0; r < 4; r++) pk[r] = f2bf(acc[mt][nt][r]);
                *(uint2*)(vt + ((size_t)(bb * NH + h) * DH + d) * NSEQ + ns) =
                    *(const uint2*)pk;
            }
        } else {
            float sc = (which == 0) ? (0.125f * LOG2E) : 1.0f;
#pragma unroll
            for (int mt = 0; mt < 4; mt++)
#pragma unroll
                for (int r = 0; r < 4; r++) {
                    int m = m0 + wr * 64 + mt * 16 + quad * 4 + r;
                    int bb = m >> 10, ns = m & 1023;
                    size_t idx = (size_t)which * QKV_PART +
                                 (((size_t)(bb * NH + h) * NSEQ + ns) << 6) + d;
                    qkv[idx] = f2bf(acc[mt][nt][r] * sc);
                }
        }
    }
}

// ---------------- proj GEMM: round-4 verbatim (best measured proj) ----------------
// m97-style: 256 thr, 64x128, BK=32, single 12KB buffer, lb(256,4), grid 768=3/CU.
#define PBM 64
#define PBN 128
__global__ __launch_bounds__(256, 4) void gemm_proj(const u16* __restrict__ A,
                                                    const u16* __restrict__ Bm,
                                                    float* __restrict__ Co) {
    __shared__ u16 As[PBM * BK];   // 4 KB
    __shared__ u16 Bs[PBN * BK];   // 8 KB
    const int tid = threadIdx.x;
    const int w = tid >> 6, lane = tid & 63, quad = lane >> 4, l16 = lane & 15;
    const int wr = w >> 1, wc = w & 1;   // 2 x 2 wave grid, each 32x64
    const int m0 = blockIdx.y * PBM;
    const int n0 = blockIdx.x * PBN;
    const int K = INNER, N = DIMC;

    const int rl = lane >> 2, cc = lane & 3;
    const int ra = w * 16 + rl;
    const u16* agp = A + (size_t)(m0 + ra) * K + ((cc - ((ra >> 1) & 3)) & 3) * 8;
    const int aslot = (w * 16) * BK;
    const u16* bgp[2]; int bslot[2];
#pragma unroll
    for (int j = 0; j < 2; j++) {
        int rb = j * 64 + w * 16 + rl;
        bgp[j] = Bm + (size_t)(n0 + rb) * K + ((cc - ((rb >> 1) & 3)) & 3) * 8;
        bslot[j] = (j * 64 + w * 16) * BK;
    }
    const int swz = ((quad + ((l16 >> 1) & 3)) & 3) * 8;
    int aoff[2], boff[4];
#pragma unroll
    for (int t = 0; t < 2; t++) aoff[t] = (wr * 32 + t * 16 + l16) * BK + swz;
#pragma unroll
    for (int t = 0; t < 4; t++) boff[t] = (wc * 64 + t * 16 + l16) * BK + swz;

    f32x4 acc[2][4] = {};
    const int NIT = K / BK;   // 24
    for (int it = 0; it < NIT; ++it) {
        int kt = it * BK;
        async16(&As[aslot], agp + kt);
        async16(&Bs[bslot[0]], bgp[0] + kt);
        async16(&Bs[bslot[1]], bgp[1] + kt);
        __syncthreads();
        short8 af[2], bf[4];
#pragma unroll
        for (int t = 0; t < 2; t++) af[t] = *(const short8*)(&As[aoff[t]]);
#pragma unroll
        for (int t = 0; t < 4; t++) bf[t] = *(const short8*)(&Bs[boff[t]]);
#pragma unroll
        for (int mt = 0; mt < 2; mt++)
#pragma unroll
            for (int nt = 0; nt < 4; nt++)
                acc[mt][nt] = __builtin_amdgcn_mfma_f32_16x16x32_bf16(af[mt], bf[nt],
                                                                      acc[mt][nt], 0, 0, 0);
        __syncthreads();
    }
#pragma unroll
    for (int mt = 0; mt < 2; mt++)
#pragma unroll
        for (int nt = 0; nt < 4; nt++) {
            int o = n0 + wc * 64 + nt * 16 + l16;
#pragma unroll
            for (int r = 0; r < 4; r++) {
                int m = m0 + wr * 32 + mt * 16 + quad * 4 + r;
                Co[(size_t)m * N + o] = acc[mt][nt][r];
            }
        }
}

// ---------------- Flash attention: round-3/6 verbatim (staged, counted vmcnt) -----
__global__ __launch_bounds__(256) void attn_kernel(const u16* __restrict__ qkv,
                                                   u16* __restrict__ attn) {
    __shared__ u16 Ks[3][64 * 64];   // rows: key pos, cols: d  (rotated 16B chunks)
    __shared__ u16 Vs[3][64 * 64];   // rows: d, cols: key pos  (rotated 16B chunks)

    const int tid = threadIdx.x;
    const int w = tid >> 6, lane = tid & 63, quad = lane >> 4, l16 = lane & 15;
    const int bh = blockIdx.x, qt = blockIdx.y;
    const size_t headoff = (size_t)bh * NSEQ * DH;
    const u16* Qp = qkv + headoff;
    const u16* Kp = qkv + QKV_PART + headoff;
    const u16* Vtp = qkv + 2 * QKV_PART + headoff;
    const int q0 = qt * 128 + w * 32;

    const int rl8 = lane >> 3, cc8 = lane & 7;
    const u16* kg[2]; const u16* vg[2]; int ksl[2];
#pragma unroll
    for (int j = 0; j < 2; j++) {
        int r = w * 16 + j * 8 + rl8;
        int c = ((cc8 - r) & 7) * 8;
        kg[j] = Kp + (size_t)r * DH + c;
        vg[j] = Vtp + (size_t)r * NSEQ + c;
        ksl[j] = (w * 16 + j * 8) * 64;
    }

    const int sw0 = ((quad + l16) & 7) * 8;
    const int sw1 = ((quad + 4 + l16) & 7) * 8;

    // Q loads FIRST, pinned complete BEFORE any async16 is issued
    short8 qf[2][2];
#pragma unroll
    for (int mf = 0; mf < 2; mf++) {
        qf[mf][0] = *(const short8*)(Qp + (size_t)(q0 + mf * 16 + l16) * DH + quad * 8);
        qf[mf][1] = *(const short8*)(Qp + (size_t)(q0 + mf * 16 + l16) * DH + 32 + quad * 8);
    }
    asm volatile("" :: "v"(qf[0][0]), "v"(qf[0][1]), "v"(qf[1][0]), "v"(qf[1][1]));

    // prefetch tiles 0..2 (4 loads each)
#pragma unroll
    for (int tt = 0; tt < 3; tt++) {
        int kt = tt * 64;
#pragma unroll
        for (int j = 0; j < 2; j++) {
            async16(&Ks[tt][ksl[j]], kg[j] + (size_t)kt * DH);
            async16(&Vs[tt][ksl[j]], vg[j] + kt);
        }
    }

    f32x4 oacc[2][4] = {};          // O^T[d][q]
    float lsum[2] = {0.f, 0.f};

    const int NIT = NSEQ / 64;   // 16
    int cur = 0;
    for (int it = 0; it < NIT; ++it) {
        if (it < NIT - 1) wait_vm<4>();  // tile it landed; tile it+1 in flight
        else              wait_vm<0>();
        block_barrier();
        if (it >= 1 && it < NIT - 2) {
            int pre = cur + 2; if (pre >= 3) pre -= 3;
            int ktn = (it + 2) * 64;
#pragma unroll
            for (int j = 0; j < 2; j++) {
                async16(&Ks[pre][ksl[j]], kg[j] + (size_t)ktn * DH);
                async16(&Vs[pre][ksl[j]], vg[j] + ktn);
            }
        }

        short8 kf[4][2];
#pragma unroll
        for (int nt = 0; nt < 4; nt++) {
            const u16* kr = &Ks[cur][(nt * 16 + l16) * 64];
            kf[nt][0] = *(const short8*)(kr + sw0);
            kf[nt][1] = *(const short8*)(kr + sw1);
        }
        short4v vf[4][4];
#pragma unroll
        for (int nt2 = 0; nt2 < 4; nt2++) {
            int row = nt2 * 16 + l16;
#pragma unroll
            for (int c = 0; c < 4; c++) {
                int off = row * 64 + (((c * 2 + (quad >> 1) + row) & 7) << 3) + (quad & 1) * 4;
                vf[nt2][c] = *(const short4v*)(&Vs[cur][off]);
            }
        }

#pragma unroll
        for (int mf = 0; mf < 2; mf++) {
            f32x4 st[4];
#pragma unroll
            for (int nt = 0; nt < 4; nt++) {
                f32x4 z = {};
                z = __builtin_amdgcn_mfma_f32_16x16x32_bf16(kf[nt][0], qf[mf][0], z, 0, 0, 0);
                z = __builtin_amdgcn_mfma_f32_16x16x32_bf16(kf[nt][1], qf[mf][1], z, 0, 0, 0);
                st[nt] = z;
            }
            short4v pf[4];
#pragma unroll
            for (int c = 0; c < 4; c++) {
                float p0 = __builtin_amdgcn_exp2f(st[c][0]);
                float p1 = __builtin_amdgcn_exp2f(st[c][1]);
                float p2 = __builtin_amdgcn_exp2f(st[c][2]);
                float p3 = __builtin_amdgcn_exp2f(st[c][3]);
                lsum[mf] += (p0 + p1) + (p2 + p3);
                uint2 u = {pkbf(p0, p1), pkbf(p2, p3)};
                pf[c] = __builtin_bit_cast(short4v, u);
            }
#pragma unroll
            for (int nt2 = 0; nt2 < 4; nt2++)
#pragma unroll
                for (int c = 0; c < 4; c++)
                    oacc[mf][nt2] = mfma16(vf[nt2][c], pf[c], oacc[mf][nt2]);
        }
        cur = (cur == 2) ? 0 : cur + 1;
    }

#pragma unroll
    for (int mf = 0; mf < 2; mf++) {
        float v = lsum[mf];
        v += __shfl_xor(v, 16);
        v += __shfl_xor(v, 32);
        lsum[mf] = 1.0f / v;
    }

    const int b = bh / NH, h = bh - (bh / NH) * NH;
#pragma unroll
    for (int mf = 0; mf < 2; mf++) {
        int q = q0 + mf * 16 + l16;
        float inv = lsum[mf];
#pragma unroll
        for (int nt2 = 0; nt2 < 4; nt2++) {
            uint2 u = {pkbf(oacc[mf][nt2][0] * inv, oacc[mf][nt2][1] * inv),
                       pkbf(oacc[mf][nt2][2] * inv, oacc[mf][nt2][3] * inv)};
            int d = nt2 * 16 + quad * 4;
            *(uint2*)(attn + ((size_t)(b * NSEQ + q)) * INNER + h * DH + d) = u;
        }
    }
}

extern "C" void kernel_launch(void* const* d_in, const int* in_sizes, int n_in,
                              void* d_out, int out_size, void* d_ws, size_t ws_size,
                              hipStream_t stream) {
    const float* x = (const float*)d_in[0];
    const float* w_qkv = (const float*)d_in[1];
    const float* w_proj = (const float*)d_in[2];
    float* out = (float*)d_out;

    u16* xb = (u16*)d_ws;
    u16* wqkvb = xb + 6291456;
    u16* wprojb = wqkvb + 1769472;
    u16* qkvb = wprojb + 589824;
    u16* attnb = qkvb + 18874368;

    cvt_all<<<NCVT / 256, 256, 0, stream>>>(x, w_qkv, w_proj, xb, wqkvb, wprojb);

    dim3 g1(QKVN / 256, MTOT / 128);   // (9, 64), 512 threads
    gemm_qkv<<<g1, 512, 0, stream>>>(xb, wqkvb, qkvb);

    dim3 g2(HEADS_TOT, NSEQ / 128);    // (96, 8) — same-head blocks co-XCD
    attn_kernel<<<g2, 256, 0, stream>>>(qkvb, attnb);

    dim3 g3(INNER / PBN, MTOT / PBM);  // (6, 128), 3 blocks/CU exact
    gemm_proj<<<g3, 256, 0, stream>>>(attnb, wprojb, out);
}

// Round 9
// 180.115 us; speedup vs baseline: 1.5190x; 1.0191x over previous
//
#include <hip/hip_runtime.h>
#include <stdint.h>

typedef unsigned short u16;
typedef __attribute__((ext_vector_type(8))) short short8;
typedef __attribute__((ext_vector_type(4))) short short4v;
typedef __attribute__((ext_vector_type(4))) float f32x4;

#define LOG2E 1.44269504088896340736f

#define Bb 8
#define NSEQ 1024
#define DIMC 768
#define NH 12
#define DH 64
#define INNER 768
#define MTOT (Bb*NSEQ)      /* 8192 */
#define QKVN (3*INNER)      /* 2304 */
#define HEADS_TOT (Bb*NH)   /* 96 */
#define QKV_PART ((size_t)Bb*NH*NSEQ*DH)

static __device__ inline u16 f2bf(float f) {
    uint32_t u = __builtin_bit_cast(uint32_t, f);
    uint32_t r = (u + 0x7fffu + ((u >> 16) & 1u)) >> 16;
    return (u16)r;
}

// pack two f32 -> bf16 pair (round-half-up) in 3 VALU ops via v_perm
static __device__ __forceinline__ uint32_t pkbf(float f0, float f1) {
    uint32_t u0 = __builtin_bit_cast(uint32_t, f0) + 0x8000u;
    uint32_t u1 = __builtin_bit_cast(uint32_t, f1) + 0x8000u;
    return __builtin_amdgcn_perm(u1, u0, 0x07060302u);
}

// 16x16x16 bf16 MFMA: B-operand k-packing matches 16x16 MFMA C-layout
#if __has_builtin(__builtin_amdgcn_mfma_f32_16x16x16bf16_1k)
static __device__ __forceinline__ f32x4 mfma16(short4v a, short4v b, f32x4 c) {
    return __builtin_amdgcn_mfma_f32_16x16x16bf16_1k(a, b, c, 0, 0, 0);
}
#else
static __device__ __forceinline__ f32x4 mfma16(short4v a, short4v b, f32x4 c) {
    asm volatile("v_mfma_f32_16x16x16_bf16 %0, %1, %2, %0\n\ts_nop 7\n\ts_nop 7"
                 : "+v"(c) : "v"(a), "v"(b));
    return c;
}
#endif

// ---- async global->LDS, 16B per lane; keeps staged data OUT of the VGPR file ----
typedef __attribute__((address_space(1))) const void gas_void;
typedef __attribute__((address_space(3))) void las_void;
static __device__ __forceinline__ void async16(u16* lds, const u16* g) {
    __builtin_amdgcn_global_load_lds((gas_void*)(uintptr_t)g,
                                     (las_void*)(uintptr_t)lds, 16, 0, 0);
}

// counted vmcnt wait: N = my loads allowed to remain in flight.
// gfx9 vmcnt is 6 bits: [3:0] at simm[3:0], [5:4] at simm[15:14].
template <int N>
static __device__ __forceinline__ void wait_vm() {
    constexpr int simm = 0x0f70 | (N & 15) | ((N >> 4) << 14);
    __builtin_amdgcn_s_waitcnt(simm);
}

static __device__ __forceinline__ void block_barrier() {
    __builtin_amdgcn_s_barrier();
    __builtin_amdgcn_sched_barrier(0);
}

// SESSION LEDGER (hard-measured, do not re-try):
//  - s_setprio in these lockstep loops: TOXIC (R5: qkv 46.6 -> 62.8 us).
//  - attn LDS-free direct-global K/V: TOXIC (R7: attn ~44 -> 139 us; L2-resident
//    but latency-bound serial load->MFMA chain). Staged async16 + counted vmcnt
//    is the required structure.
//  - qkv alternates (fat-wave, reg-dbuf, m97-small-tile): all <= round-1 form.
//  - R8 composition reproduced 183.55 us (session best). This round: only change
//    is T1 XCD-grouping on gemm_proj's block map (bijective; correctness-safe).

// ---------------- fused fp32 -> bf16 conversion (single dispatch) ----------------
#define NX8  786432
#define NWQ8 221184
#define NWP8 73728
#define NCVT (NX8 + NWQ8 + NWP8)
__global__ __launch_bounds__(256) void cvt_all(const float* __restrict__ x,
                                               const float* __restrict__ wq,
                                               const float* __restrict__ wp,
                                               u16* __restrict__ xb,
                                               u16* __restrict__ wqb,
                                               u16* __restrict__ wpb) {
    int i = blockIdx.x * 256 + threadIdx.x;
    const float* s; u16* d; int j;
    if (i < NX8) { s = x; d = xb; j = i; }
    else if (i < NX8 + NWQ8) { s = wq; d = wqb; j = i - NX8; }
    else { s = wp; d = wpb; j = i - NX8 - NWQ8; }
    const float4* s4 = (const float4*)s;
    float4 a = s4[2 * j], b = s4[2 * j + 1];
    float v[8] = {a.x, a.y, a.z, a.w, b.x, b.y, b.z, b.w};
    u16 o[8];
#pragma unroll
    for (int t = 0; t < 8; t++) o[t] = f2bf(v[t]);
    ((uint4*)d)[j] = *(const uint4*)o;
}

// ---------------- QKV GEMM: round-1 verbatim (best measured: 45.0-46.6 us) --------
// 512 thr, 128x256, BK=32, 3-buffer counted-vmcnt pipeline. Raw s_barrier, no
// sched_barrier, no setprio.
#define BK 32
__global__ __launch_bounds__(512, 4) void gemm_qkv(const u16* __restrict__ A,
                                                   const u16* __restrict__ Bm,
                                                   u16* __restrict__ qkv) {
    __shared__ u16 As[3][128 * BK];   // 3 x 8 KB
    __shared__ u16 Bs[3][256 * BK];   // 3 x 16 KB  (72 KB total -> 2 blocks/CU)
    const int tid = threadIdx.x;
    const int w = tid >> 6, lane = tid & 63, quad = lane >> 4, l16 = lane & 15;
    const int wr = w >> 2, wc = w & 3;           // 2 x 4 wave grid, 64x64 each
    const int bid = blockIdx.x + 9 * blockIdx.y; // 0..575
    const int xcd = bid & 7, j9 = bid >> 3;      // j9 in 0..71
    const int m0 = (8 * xcd + j9 / 9) * 128;     // 8 consecutive m-panels per XCD
    const int n0 = (j9 % 9) * 256;
    const int K = DIMC;

    const int rl = lane >> 2, cc = lane & 3;
    const int ra = w * 16 + rl;
    const u16* agp = A + (size_t)(m0 + ra) * K + ((cc - ((ra >> 1) & 3)) & 3) * 8;
    const int aslot = (w * 16) * BK;
    const u16* bgp[2]; int bslot[2];
#pragma unroll
    for (int j = 0; j < 2; j++) {
        int rb = w * 32 + j * 16 + rl;
        bgp[j] = Bm + (size_t)(n0 + rb) * K + ((cc - ((rb >> 1) & 3)) & 3) * 8;
        bslot[j] = (w * 32 + j * 16) * BK;
    }

    const int swz = ((quad + ((l16 >> 1) & 3)) & 3) * 8;
    int aoff[4], boff[4];
#pragma unroll
    for (int t = 0; t < 4; t++) {
        aoff[t] = (wr * 64 + t * 16 + l16) * BK + swz;
        boff[t] = (wc * 64 + t * 16 + l16) * BK + swz;
    }

    // prefetch tiles 0 and 1
#pragma unroll
    for (int tt = 0; tt < 2; tt++) {
        int kt = tt * BK;
        async16(&As[tt][aslot], agp + kt);
        async16(&Bs[tt][bslot[0]], bgp[0] + kt);
        async16(&Bs[tt][bslot[1]], bgp[1] + kt);
    }

    f32x4 acc[4][4] = {};
    const int NIT = K / BK;   // 24
    int cur = 0;
    for (int it = 0; it < NIT; ++it) {
        if (it < NIT - 1) wait_vm<3>();   // tile it landed; tile it+1 stays in flight
        else              wait_vm<0>();
        __builtin_amdgcn_s_barrier();
        if (it < NIT - 2) {
            int pre = cur + 2; if (pre >= 3) pre -= 3;
            int ktn = (it + 2) * BK;
            async16(&As[pre][aslot], agp + ktn);
            async16(&Bs[pre][bslot[0]], bgp[0] + ktn);
            async16(&Bs[pre][bslot[1]], bgp[1] + ktn);
        }
        short8 af[4], bf[4];
#pragma unroll
        for (int t = 0; t < 4; t++) af[t] = *(const short8*)(&As[cur][aoff[t]]);
#pragma unroll
        for (int t = 0; t < 4; t++) bf[t] = *(const short8*)(&Bs[cur][boff[t]]);
#pragma unroll
        for (int mt = 0; mt < 4; mt++)
#pragma unroll
            for (int nt = 0; nt < 4; nt++)
                acc[mt][nt] = __builtin_amdgcn_mfma_f32_16x16x32_bf16(af[mt], bf[nt],
                                                                      acc[mt][nt], 0, 0, 0);
        cur = (cur == 2) ? 0 : cur + 1;
    }

#pragma unroll
    for (int nt = 0; nt < 4; nt++) {
        int o = n0 + wc * 64 + nt * 16 + l16;
        int which = o / 768;
        int rem = o - which * 768;
        int h = rem >> 6, d = rem & 63;
        if (which == 2) {
            u16* vt = qkv + 2 * QKV_PART;
#pragma unroll
            for (int mt = 0; mt < 4; mt++) {
                int m = m0 + wr * 64 + mt * 16 + quad * 4;
                int bb = m >> 10, ns = m & 1023;
                alignas(8) u16 pk[4];
#pragma unroll
                for (int r = 0; r < 4; r++) pk[r] = f2bf(acc[mt][nt][r]);
                *(uint2*)(vt + ((size_t)(bb * NH + h) * DH + d) * NSEQ + ns) =
                    *(const uint2*)pk;
            }
        } else {
            float sc = (which == 0) ? (0.125f * LOG2E) : 1.0f;
#pragma unroll
            for (int mt = 0; mt < 4; mt++)
#pragma unroll
                for (int r = 0; r < 4; r++) {
                    int m = m0 + wr * 64 + mt * 16 + quad * 4 + r;
                    int bb = m >> 10, ns = m & 1023;
                    size_t idx = (size_t)which * QKV_PART +
                                 (((size_t)(bb * NH + h) * NSEQ + ns) << 6) + d;
                    qkv[idx] = f2bf(acc[mt][nt][r] * sc);
                }
        }
    }
}

// ---------------- proj GEMM: round-4 structure + T1 XCD-grouped block map ---------
// m97-style: 256 thr, 64x128, BK=32, single 12KB buffer, lb(256,4), grid 768=3/CU.
// NEW: linear block id l = x + 6y round-robins XCDs, so each A m-panel (shared by
// 6 blocks) was fetched through 6 different L2s. Remap (bijective, 768=8x16x6):
// xcd = l%8 gets contiguous y' range [xcd*16, xcd*16+16) -> per-XCD footprint
// A-slice 1.5MB + w_proj 1.2MB = 2.7MB < 4MB L2; A reuse becomes XCD-local.
#define PBM 64
#define PBN 128
__global__ __launch_bounds__(256, 4) void gemm_proj(const u16* __restrict__ A,
                                                    const u16* __restrict__ Bm,
                                                    float* __restrict__ Co) {
    __shared__ u16 As[PBM * BK];   // 4 KB
    __shared__ u16 Bs[PBN * BK];   // 8 KB
    const int tid = threadIdx.x;
    const int w = tid >> 6, lane = tid & 63, quad = lane >> 4, l16 = lane & 15;
    const int wr = w >> 1, wc = w & 1;   // 2 x 2 wave grid, each 32x64
    const int lin = blockIdx.x + 6 * blockIdx.y;   // 0..767
    const int xcd = lin & 7, j = lin >> 3;         // j in 0..95
    const int yp = xcd * 16 + j / 6;               // m-panel, XCD-contiguous
    const int xp = j % 6;                          // n-panel
    const int m0 = yp * PBM;
    const int n0 = xp * PBN;
    const int K = INNER, N = DIMC;

    const int rl = lane >> 2, cc = lane & 3;
    const int ra = w * 16 + rl;
    const u16* agp = A + (size_t)(m0 + ra) * K + ((cc - ((ra >> 1) & 3)) & 3) * 8;
    const int aslot = (w * 16) * BK;
    const u16* bgp[2]; int bslot[2];
#pragma unroll
    for (int j2 = 0; j2 < 2; j2++) {
        int rb = j2 * 64 + w * 16 + rl;
        bgp[j2] = Bm + (size_t)(n0 + rb) * K + ((cc - ((rb >> 1) & 3)) & 3) * 8;
        bslot[j2] = (j2 * 64 + w * 16) * BK;
    }
    const int swz = ((quad + ((l16 >> 1) & 3)) & 3) * 8;
    int aoff[2], boff[4];
#pragma unroll
    for (int t = 0; t < 2; t++) aoff[t] = (wr * 32 + t * 16 + l16) * BK + swz;
#pragma unroll
    for (int t = 0; t < 4; t++) boff[t] = (wc * 64 + t * 16 + l16) * BK + swz;

    f32x4 acc[2][4] = {};
    const int NIT = K / BK;   // 24
    for (int it = 0; it < NIT; ++it) {
        int kt = it * BK;
        async16(&As[aslot], agp + kt);
        async16(&Bs[bslot[0]], bgp[0] + kt);
        async16(&Bs[bslot[1]], bgp[1] + kt);
        __syncthreads();
        short8 af[2], bf[4];
#pragma unroll
        for (int t = 0; t < 2; t++) af[t] = *(const short8*)(&As[aoff[t]]);
#pragma unroll
        for (int t = 0; t < 4; t++) bf[t] = *(const short8*)(&Bs[boff[t]]);
#pragma unroll
        for (int mt = 0; mt < 2; mt++)
#pragma unroll
            for (int nt = 0; nt < 4; nt++)
                acc[mt][nt] = __builtin_amdgcn_mfma_f32_16x16x32_bf16(af[mt], bf[nt],
                                                                      acc[mt][nt], 0, 0, 0);
        __syncthreads();
    }
#pragma unroll
    for (int mt = 0; mt < 2; mt++)
#pragma unroll
        for (int nt = 0; nt < 4; nt++) {
            int o = n0 + wc * 64 + nt * 16 + l16;
#pragma unroll
            for (int r = 0; r < 4; r++) {
                int m = m0 + wr * 32 + mt * 16 + quad * 4 + r;
                Co[(size_t)m * N + o] = acc[mt][nt][r];
            }
        }
}

// ---------------- Flash attention: round-3/6 verbatim (staged, counted vmcnt) -----
__global__ __launch_bounds__(256) void attn_kernel(const u16* __restrict__ qkv,
                                                   u16* __restrict__ attn) {
    __shared__ u16 Ks[3][64 * 64];   // rows: key pos, cols: d  (rotated 16B chunks)
    __shared__ u16 Vs[3][64 * 64];   // rows: d, cols: key pos  (rotated 16B chunks)

    const int tid = threadIdx.x;
    const int w = tid >> 6, lane = tid & 63, quad = lane >> 4, l16 = lane & 15;
    const int bh = blockIdx.x, qt = blockIdx.y;
    const size_t headoff = (size_t)bh * NSEQ * DH;
    const u16* Qp = qkv + headoff;
    const u16* Kp = qkv + QKV_PART + headoff;
    const u16* Vtp = qkv + 2 * QKV_PART + headoff;
    const int q0 = qt * 128 + w * 32;

    const int rl8 = lane >> 3, cc8 = lane & 7;
    const u16* kg[2]; const u16* vg[2]; int ksl[2];
#pragma unroll
    for (int j = 0; j < 2; j++) {
        int r = w * 16 + j * 8 + rl8;
        int c = ((cc8 - r) & 7) * 8;
        kg[j] = Kp + (size_t)r * DH + c;
        vg[j] = Vtp + (size_t)r * NSEQ + c;
        ksl[j] = (w * 16 + j * 8) * 64;
    }

    const int sw0 = ((quad + l16) & 7) * 8;
    const int sw1 = ((quad + 4 + l16) & 7) * 8;

    // Q loads FIRST, pinned complete BEFORE any async16 is issued
    short8 qf[2][2];
#pragma unroll
    for (int mf = 0; mf < 2; mf++) {
        qf[mf][0] = *(const short8*)(Qp + (size_t)(q0 + mf * 16 + l16) * DH + quad * 8);
        qf[mf][1] = *(const short8*)(Qp + (size_t)(q0 + mf * 16 + l16) * DH + 32 + quad * 8);
    }
    asm volatile("" :: "v"(qf[0][0]), "v"(qf[0][1]), "v"(qf[1][0]), "v"(qf[1][1]));

    // prefetch tiles 0..2 (4 loads each)
#pragma unroll
    for (int tt = 0; tt < 3; tt++) {
        int kt = tt * 64;
#pragma unroll
        for (int j = 0; j < 2; j++) {
            async16(&Ks[tt][ksl[j]], kg[j] + (size_t)kt * DH);
            async16(&Vs[tt][ksl[j]], vg[j] + kt);
        }
    }

    f32x4 oacc[2][4] = {};          // O^T[d][q]
    float lsum[2] = {0.f, 0.f};

    const int NIT = NSEQ / 64;   // 16
    int cur = 0;
    for (int it = 0; it < NIT; ++it) {
        if (it < NIT - 1) wait_vm<4>();  // tile it landed; tile it+1 in flight
        else              wait_vm<0>();
        block_barrier();
        if (it >= 1 && it < NIT - 2) {
            int pre = cur + 2; if (pre >= 3) pre -= 3;
            int ktn = (it + 2) * 64;
#pragma unroll
            for (int j = 0; j < 2; j++) {
                async16(&Ks[pre][ksl[j]], kg[j] + (size_t)ktn * DH);
                async16(&Vs[pre][ksl[j]], vg[j] + ktn);
            }
        }

        short8 kf[4][2];
#pragma unroll
        for (int nt = 0; nt < 4; nt++) {
            const u16* kr = &Ks[cur][(nt * 16 + l16) * 64];
            kf[nt][0] = *(const short8*)(kr + sw0);
            kf[nt][1] = *(const short8*)(kr + sw1);
        }
        short4v vf[4][4];
#pragma unroll
        for (int nt2 = 0; nt2 < 4; nt2++) {
            int row = nt2 * 16 + l16;
#pragma unroll
            for (int c = 0; c < 4; c++) {
                int off = row * 64 + (((c * 2 + (quad >> 1) + row) & 7) << 3) + (quad & 1) * 4;
                vf[nt2][c] = *(const short4v*)(&Vs[cur][off]);
            }
        }

#pragma unroll
        for (int mf = 0; mf < 2; mf++) {
            f32x4 st[4];
#pragma unroll
            for (int nt = 0; nt < 4; nt++) {
                f32x4 z = {};
                z = __builtin_amdgcn_mfma_f32_16x16x32_bf16(kf[nt][0], qf[mf][0], z, 0, 0, 0);
                z = __builtin_amdgcn_mfma_f32_16x16x32_bf16(kf[nt][1], qf[mf][1], z, 0, 0, 0);
                st[nt] = z;
            }
            short4v pf[4];
#pragma unroll
            for (int c = 0; c < 4; c++) {
                float p0 = __builtin_amdgcn_exp2f(st[c][0]);
                float p1 = __builtin_amdgcn_exp2f(st[c][1]);
                float p2 = __builtin_amdgcn_exp2f(st[c][2]);
                float p3 = __builtin_amdgcn_exp2f(st[c][3]);
                lsum[mf] += (p0 + p1) + (p2 + p3);
                uint2 u = {pkbf(p0, p1), pkbf(p2, p3)};
                pf[c] = __builtin_bit_cast(short4v, u);
            }
#pragma unroll
            for (int nt2 = 0; nt2 < 4; nt2++)
#pragma unroll
                for (int c = 0; c < 4; c++)
                    oacc[mf][nt2] = mfma16(vf[nt2][c], pf[c], oacc[mf][nt2]);
        }
        cur = (cur == 2) ? 0 : cur + 1;
    }

#pragma unroll
    for (int mf = 0; mf < 2; mf++) {
        float v = lsum[mf];
        v += __shfl_xor(v, 16);
        v += __shfl_xor(v, 32);
        lsum[mf] = 1.0f / v;
    }

    const int b = bh / NH, h = bh - (bh / NH) * NH;
#pragma unroll
    for (int mf = 0; mf < 2; mf++) {
        int q = q0 + mf * 16 + l16;
        float inv = lsum[mf];
#pragma unroll
        for (int nt2 = 0; nt2 < 4; nt2++) {
            uint2 u = {pkbf(oacc[mf][nt2][0] * inv, oacc[mf][nt2][1] * inv),
                       pkbf(oacc[mf][nt2][2] * inv, oacc[mf][nt2][3] * inv)};
            int d = nt2 * 16 + quad * 4;
            *(uint2*)(attn + ((size_t)(b * NSEQ + q)) * INNER + h * DH + d) = u;
        }
    }
}

extern "C" void kernel_launch(void* const* d_in, const int* in_sizes, int n_in,
                              void* d_out, int out_size, void* d_ws, size_t ws_size,
                              hipStream_t stream) {
    const float* x = (const float*)d_in[0];
    const float* w_qkv = (const float*)d_in[1];
    const float* w_proj = (const float*)d_in[2];
    float* out = (float*)d_out;

    u16* xb = (u16*)d_ws;
    u16* wqkvb = xb + 6291456;
    u16* wprojb = wqkvb + 1769472;
    u16* qkvb = wprojb + 589824;
    u16* attnb = qkvb + 18874368;

    cvt_all<<<NCVT / 256, 256, 0, stream>>>(x, w_qkv, w_proj, xb, wqkvb, wprojb);

    dim3 g1(QKVN / 256, MTOT / 128);   // (9, 64), 512 threads
    gemm_qkv<<<g1, 512, 0, stream>>>(xb, wqkvb, qkvb);

    dim3 g2(HEADS_TOT, NSEQ / 128);    // (96, 8) — same-head blocks co-XCD
    attn_kernel<<<g2, 256, 0, stream>>>(qkvb, attnb);

    dim3 g3(INNER / PBN, MTOT / PBM);  // (6, 128), 3 blocks/CU, XCD-grouped in-kernel
    gemm_proj<<<g3, 256, 0, stream>>>(attnb, wprojb, out);
}

// Round 10
// 174.530 us; speedup vs baseline: 1.5676x; 1.0320x over previous
//
#include <hip/hip_runtime.h>
#include <stdint.h>

typedef unsigned short u16;
typedef __attribute__((ext_vector_type(8))) short short8;
typedef __attribute__((ext_vector_type(4))) short short4v;
typedef __attribute__((ext_vector_type(4))) float f32x4;

#define LOG2E 1.44269504088896340736f

#define Bb 8
#define NSEQ 1024
#define DIMC 768
#define NH 12
#define DH 64
#define INNER 768
#define MTOT (Bb*NSEQ)      /* 8192 */
#define QKVN (3*INNER)      /* 2304 */
#define HEADS_TOT (Bb*NH)   /* 96 */
#define QKV_PART ((size_t)Bb*NH*NSEQ*DH)

static __device__ inline u16 f2bf(float f) {
    uint32_t u = __builtin_bit_cast(uint32_t, f);
    uint32_t r = (u + 0x7fffu + ((u >> 16) & 1u)) >> 16;
    return (u16)r;
}

// pack two f32 -> bf16 pair (round-half-up) in 3 VALU ops via v_perm
static __device__ __forceinline__ uint32_t pkbf(float f0, float f1) {
    uint32_t u0 = __builtin_bit_cast(uint32_t, f0) + 0x8000u;
    uint32_t u1 = __builtin_bit_cast(uint32_t, f1) + 0x8000u;
    return __builtin_amdgcn_perm(u1, u0, 0x07060302u);
}

// 16x16x16 bf16 MFMA: B-operand k-packing matches 16x16 MFMA C-layout
#if __has_builtin(__builtin_amdgcn_mfma_f32_16x16x16bf16_1k)
static __device__ __forceinline__ f32x4 mfma16(short4v a, short4v b, f32x4 c) {
    return __builtin_amdgcn_mfma_f32_16x16x16bf16_1k(a, b, c, 0, 0, 0);
}
#else
static __device__ __forceinline__ f32x4 mfma16(short4v a, short4v b, f32x4 c) {
    asm volatile("v_mfma_f32_16x16x16_bf16 %0, %1, %2, %0\n\ts_nop 7\n\ts_nop 7"
                 : "+v"(c) : "v"(a), "v"(b));
    return c;
}
#endif

// ---- async global->LDS, 16B per lane; keeps staged data OUT of the VGPR file ----
typedef __attribute__((address_space(1))) const void gas_void;
typedef __attribute__((address_space(3))) void las_void;
static __device__ __forceinline__ void async16(u16* lds, const u16* g) {
    __builtin_amdgcn_global_load_lds((gas_void*)(uintptr_t)g,
                                     (las_void*)(uintptr_t)lds, 16, 0, 0);
}

// counted vmcnt wait: N = my loads allowed to remain in flight.
// gfx9 vmcnt is 6 bits: [3:0] at simm[3:0], [5:4] at simm[15:14].
template <int N>
static __device__ __forceinline__ void wait_vm() {
    constexpr int simm = 0x0f70 | (N & 15) | ((N >> 4) << 14);
    __builtin_amdgcn_s_waitcnt(simm);
}

static __device__ __forceinline__ void block_barrier() {
    __builtin_amdgcn_s_barrier();
    __builtin_amdgcn_sched_barrier(0);
}

// SESSION LEDGER (hard-measured, do not re-try):
//  - s_setprio in these lockstep loops: TOXIC (R5: qkv 46.6 -> 62.8 us).
//  - attn LDS-free direct-global K/V: TOXIC (R7: attn ~44 -> 139 us).
//  - qkv loop alternates (fat-wave, reg-dbuf, m97-small-tile): all <= round-1 form.
//  - R9: proj XCD-grouping WIN (183.55 -> 180.1). Kept.
//  - R10 (this round): qkv grid balance 576 blocks (2.25/CU, 64 CUs run 3 blocks
//    -> tail) retiled to 128x192 x 768 blocks = exactly 3/CU. Loop structure
//    byte-identical to round-1; only geometry + per-wave staging split changes.

// ---------------- fused fp32 -> bf16 conversion (single dispatch) ----------------
#define NX8  786432
#define NWQ8 221184
#define NWP8 73728
#define NCVT (NX8 + NWQ8 + NWP8)
__global__ __launch_bounds__(256) void cvt_all(const float* __restrict__ x,
                                               const float* __restrict__ wq,
                                               const float* __restrict__ wp,
                                               u16* __restrict__ xb,
                                               u16* __restrict__ wqb,
                                               u16* __restrict__ wpb) {
    int i = blockIdx.x * 256 + threadIdx.x;
    const float* s; u16* d; int j;
    if (i < NX8) { s = x; d = xb; j = i; }
    else if (i < NX8 + NWQ8) { s = wq; d = wqb; j = i - NX8; }
    else { s = wp; d = wpb; j = i - NX8 - NWQ8; }
    const float4* s4 = (const float4*)s;
    float4 a = s4[2 * j], b = s4[2 * j + 1];
    float v[8] = {a.x, a.y, a.z, a.w, b.x, b.y, b.z, b.w};
    u16 o[8];
#pragma unroll
    for (int t = 0; t < 8; t++) o[t] = f2bf(v[t]);
    ((uint4*)d)[j] = *(const uint4*)o;
}

// ---------------- QKV GEMM: 512 thr, 128x192, BK=32, 3-buf counted vmcnt ----------
// Round-10: same round-1 pipeline; tile 128x256 -> 128x192 so grid = 768 blocks
// = exactly 3/CU (uniform; old 576 = 2.25/CU left 64 CUs running a 3rd block while
// 192 idled). 8 waves in 2x4 grid, each 64x48 (4x3 frags, 12 MFMA/iter).
// B tile = 192 rows = 12 wave-shots: waves 0-3 stage 2 B-shots, waves 4-7 one ->
// per-wave async16/tile = 3 (w<4) or 2 (w>=4); counted waits split accordingly
// (vmcnt is per-wave). XCD map bijective: 96 = 8 m-panels x 12 n-panels per XCD.
#define BK 32
__global__ __launch_bounds__(512, 4) void gemm_qkv(const u16* __restrict__ A,
                                                   const u16* __restrict__ Bm,
                                                   u16* __restrict__ qkv) {
    __shared__ u16 As[3][128 * BK];   // 3 x 8 KB
    __shared__ u16 Bs[3][192 * BK];   // 3 x 12 KB  (60 KB total -> 2 blocks/CU)
    const int tid = threadIdx.x;
    const int w = tid >> 6, lane = tid & 63, quad = lane >> 4, l16 = lane & 15;
    const int wr = w >> 2, wc = w & 3;            // 2 x 4 wave grid, 64x48 each
    const int bid = blockIdx.x + 12 * blockIdx.y; // 0..767
    const int xcd = bid & 7, j12 = bid >> 3;      // j12 in 0..95
    const int m0 = (8 * xcd + j12 / 12) * 128;    // 8 consecutive m-panels per XCD
    const int n0 = (j12 % 12) * 192;
    const int K = DIMC;

    const int rl = lane >> 2, cc = lane & 3;
    // A: one shot, 8 waves x 16 rows = 128 rows (round-1 pattern unchanged)
    const int ra = w * 16 + rl;
    const u16* agp = A + (size_t)(m0 + ra) * K + ((cc - ((ra >> 1) & 3)) & 3) * 8;
    const int aslot = (w * 16) * BK;
    // B: shot 0 rows w*16 (all waves, 0..127); shot 1 rows 128+w*16 (waves 0-3 only)
    const u16* bgp[2]; int bslot[2];
#pragma unroll
    for (int j = 0; j < 2; j++) {
        int rb = j * 128 + w * 16 + rl;           // LDS-relative row
        bgp[j] = Bm + (size_t)(n0 + rb) * K + ((cc - ((rb >> 1) & 3)) & 3) * 8;
        bslot[j] = (j * 128 + w * 16) * BK;
    }
    const bool b2 = (w < 4);   // wave-uniform: this wave stages 2 B-shots

    const int swz = ((quad + ((l16 >> 1) & 3)) & 3) * 8;
    int aoff[4], boff[3];
#pragma unroll
    for (int t = 0; t < 4; t++) aoff[t] = (wr * 64 + t * 16 + l16) * BK + swz;
#pragma unroll
    for (int t = 0; t < 3; t++) boff[t] = (wc * 48 + t * 16 + l16) * BK + swz;

    // prefetch tiles 0 and 1
#pragma unroll
    for (int tt = 0; tt < 2; tt++) {
        int kt = tt * BK;
        async16(&As[tt][aslot], agp + kt);
        async16(&Bs[tt][bslot[0]], bgp[0] + kt);
        if (b2) async16(&Bs[tt][bslot[1]], bgp[1] + kt);
    }

    f32x4 acc[4][3] = {};
    const int NIT = K / BK;   // 24
    int cur = 0;
    for (int it = 0; it < NIT; ++it) {
        if (it < NIT - 1) {               // tile it landed; tile it+1 stays in flight
            if (b2) wait_vm<3>(); else wait_vm<2>();
        } else {
            wait_vm<0>();
        }
        __builtin_amdgcn_s_barrier();
        if (it < NIT - 2) {
            int pre = cur + 2; if (pre >= 3) pre -= 3;
            int ktn = (it + 2) * BK;
            async16(&As[pre][aslot], agp + ktn);
            async16(&Bs[pre][bslot[0]], bgp[0] + ktn);
            if (b2) async16(&Bs[pre][bslot[1]], bgp[1] + ktn);
        }
        short8 af[4], bf[3];
#pragma unroll
        for (int t = 0; t < 4; t++) af[t] = *(const short8*)(&As[cur][aoff[t]]);
#pragma unroll
        for (int t = 0; t < 3; t++) bf[t] = *(const short8*)(&Bs[cur][boff[t]]);
#pragma unroll
        for (int mt = 0; mt < 4; mt++)
#pragma unroll
            for (int nt = 0; nt < 3; nt++)
                acc[mt][nt] = __builtin_amdgcn_mfma_f32_16x16x32_bf16(af[mt], bf[nt],
                                                                      acc[mt][nt], 0, 0, 0);
        cur = (cur == 2) ? 0 : cur + 1;
    }

#pragma unroll
    for (int nt = 0; nt < 3; nt++) {
        int o = n0 + wc * 48 + nt * 16 + l16;
        int which = o / 768;
        int rem = o - which * 768;
        int h = rem >> 6, d = rem & 63;
        if (which == 2) {
            u16* vt = qkv + 2 * QKV_PART;
#pragma unroll
            for (int mt = 0; mt < 4; mt++) {
                int m = m0 + wr * 64 + mt * 16 + quad * 4;
                int bb = m >> 10, ns = m & 1023;
                alignas(8) u16 pk[4];
#pragma unroll
                for (int r = 0; r < 4; r++) pk[r] = f2bf(acc[mt][nt][r]);
                *(uint2*)(vt + ((size_t)(bb * NH + h) * DH + d) * NSEQ + ns) =
                    *(const uint2*)pk;
            }
        } else {
            float sc = (which == 0) ? (0.125f * LOG2E) : 1.0f;
#pragma unroll
            for (int mt = 0; mt < 4; mt++)
#pragma unroll
                for (int r = 0; r < 4; r++) {
                    int m = m0 + wr * 64 + mt * 16 + quad * 4 + r;
                    int bb = m >> 10, ns = m & 1023;
                    size_t idx = (size_t)which * QKV_PART +
                                 (((size_t)(bb * NH + h) * NSEQ + ns) << 6) + d;
                    qkv[idx] = f2bf(acc[mt][nt][r] * sc);
                }
        }
    }
}

// ---------------- proj GEMM: round-9 verbatim (XCD-grouped, WIN) ------------------
#define PBM 64
#define PBN 128
__global__ __launch_bounds__(256, 4) void gemm_proj(const u16* __restrict__ A,
                                                    const u16* __restrict__ Bm,
                                                    float* __restrict__ Co) {
    __shared__ u16 As[PBM * BK];   // 4 KB
    __shared__ u16 Bs[PBN * BK];   // 8 KB
    const int tid = threadIdx.x;
    const int w = tid >> 6, lane = tid & 63, quad = lane >> 4, l16 = lane & 15;
    const int wr = w >> 1, wc = w & 1;   // 2 x 2 wave grid, each 32x64
    const int lin = blockIdx.x + 6 * blockIdx.y;   // 0..767
    const int xcd = lin & 7, j = lin >> 3;         // j in 0..95
    const int yp = xcd * 16 + j / 6;               // m-panel, XCD-contiguous
    const int xp = j % 6;                          // n-panel
    const int m0 = yp * PBM;
    const int n0 = xp * PBN;
    const int K = INNER, N = DIMC;

    const int rl = lane >> 2, cc = lane & 3;
    const int ra = w * 16 + rl;
    const u16* agp = A + (size_t)(m0 + ra) * K + ((cc - ((ra >> 1) & 3)) & 3) * 8;
    const int aslot = (w * 16) * BK;
    const u16* bgp[2]; int bslot[2];
#pragma unroll
    for (int j2 = 0; j2 < 2; j2++) {
        int rb = j2 * 64 + w * 16 + rl;
        bgp[j2] = Bm + (size_t)(n0 + rb) * K + ((cc - ((rb >> 1) & 3)) & 3) * 8;
        bslot[j2] = (j2 * 64 + w * 16) * BK;
    }
    const int swz = ((quad + ((l16 >> 1) & 3)) & 3) * 8;
    int aoff[2], boff[4];
#pragma unroll
    for (int t = 0; t < 2; t++) aoff[t] = (wr * 32 + t * 16 + l16) * BK + swz;
#pragma unroll
    for (int t = 0; t < 4; t++) boff[t] = (wc * 64 + t * 16 + l16) * BK + swz;

    f32x4 acc[2][4] = {};
    const int NIT = K / BK;   // 24
    for (int it = 0; it < NIT; ++it) {
        int kt = it * BK;
        async16(&As[aslot], agp + kt);
        async16(&Bs[bslot[0]], bgp[0] + kt);
        async16(&Bs[bslot[1]], bgp[1] + kt);
        __syncthreads();
        short8 af[2], bf[4];
#pragma unroll
        for (int t = 0; t < 2; t++) af[t] = *(const short8*)(&As[aoff[t]]);
#pragma unroll
        for (int t = 0; t < 4; t++) bf[t] = *(const short8*)(&Bs[boff[t]]);
#pragma unroll
        for (int mt = 0; mt < 2; mt++)
#pragma unroll
            for (int nt = 0; nt < 4; nt++)
                acc[mt][nt] = __builtin_amdgcn_mfma_f32_16x16x32_bf16(af[mt], bf[nt],
                                                                      acc[mt][nt], 0, 0, 0);
        __syncthreads();
    }
#pragma unroll
    for (int mt = 0; mt < 2; mt++)
#pragma unroll
        for (int nt = 0; nt < 4; nt++) {
            int o = n0 + wc * 64 + nt * 16 + l16;
#pragma unroll
            for (int r = 0; r < 4; r++) {
                int m = m0 + wr * 32 + mt * 16 + quad * 4 + r;
                Co[(size_t)m * N + o] = acc[mt][nt][r];
            }
        }
}

// ---------------- Flash attention: round-3/6 verbatim (staged, counted vmcnt) -----
__global__ __launch_bounds__(256) void attn_kernel(const u16* __restrict__ qkv,
                                                   u16* __restrict__ attn) {
    __shared__ u16 Ks[3][64 * 64];   // rows: key pos, cols: d  (rotated 16B chunks)
    __shared__ u16 Vs[3][64 * 64];   // rows: d, cols: key pos  (rotated 16B chunks)

    const int tid = threadIdx.x;
    const int w = tid >> 6, lane = tid & 63, quad = lane >> 4, l16 = lane & 15;
    const int bh = blockIdx.x, qt = blockIdx.y;
    const size_t headoff = (size_t)bh * NSEQ * DH;
    const u16* Qp = qkv + headoff;
    const u16* Kp = qkv + QKV_PART + headoff;
    const u16* Vtp = qkv + 2 * QKV_PART + headoff;
    const int q0 = qt * 128 + w * 32;

    const int rl8 = lane >> 3, cc8 = lane & 7;
    const u16* kg[2]; const u16* vg[2]; int ksl[2];
#pragma unroll
    for (int j = 0; j < 2; j++) {
        int r = w * 16 + j * 8 + rl8;
        int c = ((cc8 - r) & 7) * 8;
        kg[j] = Kp + (size_t)r * DH + c;
        vg[j] = Vtp + (size_t)r * NSEQ + c;
        ksl[j] = (w * 16 + j * 8) * 64;
    }

    const int sw0 = ((quad + l16) & 7) * 8;
    const int sw1 = ((quad + 4 + l16) & 7) * 8;

    // Q loads FIRST, pinned complete BEFORE any async16 is issued
    short8 qf[2][2];
#pragma unroll
    for (int mf = 0; mf < 2; mf++) {
        qf[mf][0] = *(const short8*)(Qp + (size_t)(q0 + mf * 16 + l16) * DH + quad * 8);
        qf[mf][1] = *(const short8*)(Qp + (size_t)(q0 + mf * 16 + l16) * DH + 32 + quad * 8);
    }
    asm volatile("" :: "v"(qf[0][0]), "v"(qf[0][1]), "v"(qf[1][0]), "v"(qf[1][1]));

    // prefetch tiles 0..2 (4 loads each)
#pragma unroll
    for (int tt = 0; tt < 3; tt++) {
        int kt = tt * 64;
#pragma unroll
        for (int j = 0; j < 2; j++) {
            async16(&Ks[tt][ksl[j]], kg[j] + (size_t)kt * DH);
            async16(&Vs[tt][ksl[j]], vg[j] + kt);
        }
    }

    f32x4 oacc[2][4] = {};          // O^T[d][q]
    float lsum[2] = {0.f, 0.f};

    const int NIT = NSEQ / 64;   // 16
    int cur = 0;
    for (int it = 0; it < NIT; ++it) {
        if (it < NIT - 1) wait_vm<4>();  // tile it landed; tile it+1 in flight
        else              wait_vm<0>();
        block_barrier();
        if (it >= 1 && it < NIT - 2) {
            int pre = cur + 2; if (pre >= 3) pre -= 3;
            int ktn = (it + 2) * 64;
#pragma unroll
            for (int j = 0; j < 2; j++) {
                async16(&Ks[pre][ksl[j]], kg[j] + (size_t)ktn * DH);
                async16(&Vs[pre][ksl[j]], vg[j] + ktn);
            }
        }

        short8 kf[4][2];
#pragma unroll
        for (int nt = 0; nt < 4; nt++) {
            const u16* kr = &Ks[cur][(nt * 16 + l16) * 64];
            kf[nt][0] = *(const short8*)(kr + sw0);
            kf[nt][1] = *(const short8*)(kr + sw1);
        }
        short4v vf[4][4];
#pragma unroll
        for (int nt2 = 0; nt2 < 4; nt2++) {
            int row = nt2 * 16 + l16;
#pragma unroll
            for (int c = 0; c < 4; c++) {
                int off = row * 64 + (((c * 2 + (quad >> 1) + row) & 7) << 3) + (quad & 1) * 4;
                vf[nt2][c] = *(const short4v*)(&Vs[cur][off]);
            }
        }

#pragma unroll
        for (int mf = 0; mf < 2; mf++) {
            f32x4 st[4];
#pragma unroll
            for (int nt = 0; nt < 4; nt++) {
                f32x4 z = {};
                z = __builtin_amdgcn_mfma_f32_16x16x32_bf16(kf[nt][0], qf[mf][0], z, 0, 0, 0);
                z = __builtin_amdgcn_mfma_f32_16x16x32_bf16(kf[nt][1], qf[mf][1], z, 0, 0, 0);
                st[nt] = z;
            }
            short4v pf[4];
#pragma unroll
            for (int c = 0; c < 4; c++) {
                float p0 = __builtin_amdgcn_exp2f(st[c][0]);
                float p1 = __builtin_amdgcn_exp2f(st[c][1]);
                float p2 = __builtin_amdgcn_exp2f(st[c][2]);
                float p3 = __builtin_amdgcn_exp2f(st[c][3]);
                lsum[mf] += (p0 + p1) + (p2 + p3);
                uint2 u = {pkbf(p0, p1), pkbf(p2, p3)};
                pf[c] = __builtin_bit_cast(short4v, u);
            }
#pragma unroll
            for (int nt2 = 0; nt2 < 4; nt2++)
#pragma unroll
                for (int c = 0; c < 4; c++)
                    oacc[mf][nt2] = mfma16(vf[nt2][c], pf[c], oacc[mf][nt2]);
        }
        cur = (cur == 2) ? 0 : cur + 1;
    }

#pragma unroll
    for (int mf = 0; mf < 2; mf++) {
        float v = lsum[mf];
        v += __shfl_xor(v, 16);
        v += __shfl_xor(v, 32);
        lsum[mf] = 1.0f / v;
    }

    const int b = bh / NH, h = bh - (bh / NH) * NH;
#pragma unroll
    for (int mf = 0; mf < 2; mf++) {
        int q = q0 + mf * 16 + l16;
        float inv = lsum[mf];
#pragma unroll
        for (int nt2 = 0; nt2 < 4; nt2++) {
            uint2 u = {pkbf(oacc[mf][nt2][0] * inv, oacc[mf][nt2][1] * inv),
                       pkbf(oacc[mf][nt2][2] * inv, oacc[mf][nt2][3] * inv)};
            int d = nt2 * 16 + quad * 4;
            *(uint2*)(attn + ((size_t)(b * NSEQ + q)) * INNER + h * DH + d) = u;
        }
    }
}

extern "C" void kernel_launch(void* const* d_in, const int* in_sizes, int n_in,
                              void* d_out, int out_size, void* d_ws, size_t ws_size,
                              hipStream_t stream) {
    const float* x = (const float*)d_in[0];
    const float* w_qkv = (const float*)d_in[1];
    const float* w_proj = (const float*)d_in[2];
    float* out = (float*)d_out;

    u16* xb = (u16*)d_ws;
    u16* wqkvb = xb + 6291456;
    u16* wprojb = wqkvb + 1769472;
    u16* qkvb = wprojb + 589824;
    u16* attnb = qkvb + 18874368;

    cvt_all<<<NCVT / 256, 256, 0, stream>>>(x, w_qkv, w_proj, xb, wqkvb, wprojb);

    dim3 g1(QKVN / 192, MTOT / 128);   // (12, 64) = 768 blocks = exactly 3/CU
    gemm_qkv<<<g1, 512, 0, stream>>>(xb, wqkvb, qkvb);

    dim3 g2(HEADS_TOT, NSEQ / 128);    // (96, 8) — same-head blocks co-XCD
    attn_kernel<<<g2, 256, 0, stream>>>(qkvb, attnb);

    dim3 g3(INNER / PBN, MTOT / PBM);  // (6, 128), 3 blocks/CU, XCD-grouped in-kernel
    gemm_proj<<<g3, 256, 0, stream>>>(attnb, wprojb, out);
}

// Round 11
// 171.873 us; speedup vs baseline: 1.5918x; 1.0155x over previous
//
#include <hip/hip_runtime.h>
#include <stdint.h>

typedef unsigned short u16;
typedef __attribute__((ext_vector_type(8))) short short8;
typedef __attribute__((ext_vector_type(4))) short short4v;
typedef __attribute__((ext_vector_type(4))) float f32x4;

#define LOG2E 1.44269504088896340736f

#define Bb 8
#define NSEQ 1024
#define DIMC 768
#define NH 12
#define DH 64
#define INNER 768
#define MTOT (Bb*NSEQ)      /* 8192 */
#define QKVN (3*INNER)      /* 2304 */
#define HEADS_TOT (Bb*NH)   /* 96 */
#define QKV_PART ((size_t)Bb*NH*NSEQ*DH)

static __device__ inline u16 f2bf(float f) {
    uint32_t u = __builtin_bit_cast(uint32_t, f);
    uint32_t r = (u + 0x7fffu + ((u >> 16) & 1u)) >> 16;
    return (u16)r;
}

// pack two f32 -> bf16 pair (round-half-up) in 3 VALU ops via v_perm
static __device__ __forceinline__ uint32_t pkbf(float f0, float f1) {
    uint32_t u0 = __builtin_bit_cast(uint32_t, f0) + 0x8000u;
    uint32_t u1 = __builtin_bit_cast(uint32_t, f1) + 0x8000u;
    return __builtin_amdgcn_perm(u1, u0, 0x07060302u);
}

// 16x16x16 bf16 MFMA: B-operand k-packing matches 16x16 MFMA C-layout
#if __has_builtin(__builtin_amdgcn_mfma_f32_16x16x16bf16_1k)
static __device__ __forceinline__ f32x4 mfma16(short4v a, short4v b, f32x4 c) {
    return __builtin_amdgcn_mfma_f32_16x16x16bf16_1k(a, b, c, 0, 0, 0);
}
#else
static __device__ __forceinline__ f32x4 mfma16(short4v a, short4v b, f32x4 c) {
    asm volatile("v_mfma_f32_16x16x16_bf16 %0, %1, %2, %0\n\ts_nop 7\n\ts_nop 7"
                 : "+v"(c) : "v"(a), "v"(b));
    return c;
}
#endif

// ---- async global->LDS, 16B per lane; keeps staged data OUT of the VGPR file ----
typedef __attribute__((address_space(1))) const void gas_void;
typedef __attribute__((address_space(3))) void las_void;
static __device__ __forceinline__ void async16(u16* lds, const u16* g) {
    __builtin_amdgcn_global_load_lds((gas_void*)(uintptr_t)g,
                                     (las_void*)(uintptr_t)lds, 16, 0, 0);
}

// counted vmcnt wait: N = my loads allowed to remain in flight.
// gfx9 vmcnt is 6 bits: [3:0] at simm[3:0], [5:4] at simm[15:14].
template <int N>
static __device__ __forceinline__ void wait_vm() {
    constexpr int simm = 0x0f70 | (N & 15) | ((N >> 4) << 14);
    __builtin_amdgcn_s_waitcnt(simm);
}

static __device__ __forceinline__ void block_barrier() {
    __builtin_amdgcn_s_barrier();
    __builtin_amdgcn_sched_barrier(0);
}

// SESSION LEDGER (hard-measured, do not re-try):
//  - s_setprio in these lockstep loops: TOXIC (R5: qkv 46.6 -> 62.8 us).
//  - attn LDS-free direct-global K/V: TOXIC (R7: attn ~44 -> 139 us).
//  - qkv loop alternates (fat-wave, reg-dbuf, m97-small-tile): all <= round-1 form.
//  - R9: proj XCD-grouping WIN (183.55 -> 180.1). R10: qkv 768-block balance WIN
//    (180.1 -> 174.5; qkv ~45.5 -> <43.3).
//  - R11 (this round): attn V-read bank conflicts (3,145,728/dispatch = exactly
//    4 cyc x 786,432 ds_read_b64: 16-lane phases confined to 16 banks by constant
//    (quad&1) half-offset). Fix: slot-level (8B) pre-swizzle of the GLOBAL V'
//    layout written by gemm_qkv: slot s=(G+d)&15 per 64-token tile. Attn staging
//    becomes linear; V-read offset row*64+((4c+quad+row)&15)*4 covers all 32
//    banks per phase. LDS stays linear (rule #21). Pipeline untouched.

// ---------------- fused fp32 -> bf16 conversion (single dispatch) ----------------
#define NX8  786432
#define NWQ8 221184
#define NWP8 73728
#define NCVT (NX8 + NWQ8 + NWP8)
__global__ __launch_bounds__(256) void cvt_all(const float* __restrict__ x,
                                               const float* __restrict__ wq,
                                               const float* __restrict__ wp,
                                               u16* __restrict__ xb,
                                               u16* __restrict__ wqb,
                                               u16* __restrict__ wpb) {
    int i = blockIdx.x * 256 + threadIdx.x;
    const float* s; u16* d; int j;
    if (i < NX8) { s = x; d = xb; j = i; }
    else if (i < NX8 + NWQ8) { s = wq; d = wqb; j = i - NX8; }
    else { s = wp; d = wpb; j = i - NX8 - NWQ8; }
    const float4* s4 = (const float4*)s;
    float4 a = s4[2 * j], b = s4[2 * j + 1];
    float v[8] = {a.x, a.y, a.z, a.w, b.x, b.y, b.z, b.w};
    u16 o[8];
#pragma unroll
    for (int t = 0; t < 8; t++) o[t] = f2bf(v[t]);
    ((uint4*)d)[j] = *(const uint4*)o;
}

// ---------------- QKV GEMM: 512 thr, 128x192, BK=32, 3-buf counted vmcnt ----------
// R10 geometry (768 blocks = exactly 3/CU). R11: V-epilogue writes the slot-swizzled
// V' layout: per head, per 64-token tile, d-row, slot s=(G+d)&15 holds tokens G*4..+3.
#define BK 32
__global__ __launch_bounds__(512, 4) void gemm_qkv(const u16* __restrict__ A,
                                                   const u16* __restrict__ Bm,
                                                   u16* __restrict__ qkv) {
    __shared__ u16 As[3][128 * BK];   // 3 x 8 KB
    __shared__ u16 Bs[3][192 * BK];   // 3 x 12 KB  (60 KB total -> 2 blocks/CU)
    const int tid = threadIdx.x;
    const int w = tid >> 6, lane = tid & 63, quad = lane >> 4, l16 = lane & 15;
    const int wr = w >> 2, wc = w & 3;            // 2 x 4 wave grid, 64x48 each
    const int bid = blockIdx.x + 12 * blockIdx.y; // 0..767
    const int xcd = bid & 7, j12 = bid >> 3;      // j12 in 0..95
    const int m0 = (8 * xcd + j12 / 12) * 128;    // 8 consecutive m-panels per XCD
    const int n0 = (j12 % 12) * 192;
    const int K = DIMC;

    const int rl = lane >> 2, cc = lane & 3;
    // A: one shot, 8 waves x 16 rows = 128 rows
    const int ra = w * 16 + rl;
    const u16* agp = A + (size_t)(m0 + ra) * K + ((cc - ((ra >> 1) & 3)) & 3) * 8;
    const int aslot = (w * 16) * BK;
    // B: shot 0 rows w*16 (all waves); shot 1 rows 128+w*16 (waves 0-3 only)
    const u16* bgp[2]; int bslot[2];
#pragma unroll
    for (int j = 0; j < 2; j++) {
        int rb = j * 128 + w * 16 + rl;
        bgp[j] = Bm + (size_t)(n0 + rb) * K + ((cc - ((rb >> 1) & 3)) & 3) * 8;
        bslot[j] = (j * 128 + w * 16) * BK;
    }
    const bool b2 = (w < 4);

    const int swz = ((quad + ((l16 >> 1) & 3)) & 3) * 8;
    int aoff[4], boff[3];
#pragma unroll
    for (int t = 0; t < 4; t++) aoff[t] = (wr * 64 + t * 16 + l16) * BK + swz;
#pragma unroll
    for (int t = 0; t < 3; t++) boff[t] = (wc * 48 + t * 16 + l16) * BK + swz;

    // prefetch tiles 0 and 1
#pragma unroll
    for (int tt = 0; tt < 2; tt++) {
        int kt = tt * BK;
        async16(&As[tt][aslot], agp + kt);
        async16(&Bs[tt][bslot[0]], bgp[0] + kt);
        if (b2) async16(&Bs[tt][bslot[1]], bgp[1] + kt);
    }

    f32x4 acc[4][3] = {};
    const int NIT = K / BK;   // 24
    int cur = 0;
    for (int it = 0; it < NIT; ++it) {
        if (it < NIT - 1) {
            if (b2) wait_vm<3>(); else wait_vm<2>();
        } else {
            wait_vm<0>();
        }
        __builtin_amdgcn_s_barrier();
        if (it < NIT - 2) {
            int pre = cur + 2; if (pre >= 3) pre -= 3;
            int ktn = (it + 2) * BK;
            async16(&As[pre][aslot], agp + ktn);
            async16(&Bs[pre][bslot[0]], bgp[0] + ktn);
            if (b2) async16(&Bs[pre][bslot[1]], bgp[1] + ktn);
        }
        short8 af[4], bf[3];
#pragma unroll
        for (int t = 0; t < 4; t++) af[t] = *(const short8*)(&As[cur][aoff[t]]);
#pragma unroll
        for (int t = 0; t < 3; t++) bf[t] = *(const short8*)(&Bs[cur][boff[t]]);
#pragma unroll
        for (int mt = 0; mt < 4; mt++)
#pragma unroll
            for (int nt = 0; nt < 3; nt++)
                acc[mt][nt] = __builtin_amdgcn_mfma_f32_16x16x32_bf16(af[mt], bf[nt],
                                                                      acc[mt][nt], 0, 0, 0);
        cur = (cur == 2) ? 0 : cur + 1;
    }

#pragma unroll
    for (int nt = 0; nt < 3; nt++) {
        int o = n0 + wc * 48 + nt * 16 + l16;
        int which = o / 768;
        int rem = o - which * 768;
        int h = rem >> 6, d = rem & 63;
        if (which == 2) {
            // V': slot-swizzled tile-blocked layout (see ledger). pk = tokens
            // ns..ns+3 of dim d -> head base + tile*4096 + d*64 + ((G+d)&15)*4.
            u16* vt = qkv + 2 * QKV_PART;
#pragma unroll
            for (int mt = 0; mt < 4; mt++) {
                int m = m0 + wr * 64 + mt * 16 + quad * 4;
                int bb = m >> 10, ns = m & 1023;
                int tile = ns >> 6, G = (ns >> 2) & 15;
                alignas(8) u16 pk[4];
#pragma unroll
                for (int r = 0; r < 4; r++) pk[r] = f2bf(acc[mt][nt][r]);
                size_t addr = (size_t)(bb * NH + h) * (NSEQ * DH)
                            + (size_t)tile * 4096 + d * 64 + (((G + d) & 15) << 2);
                *(uint2*)(vt + addr) = *(const uint2*)pk;
            }
        } else {
            float sc = (which == 0) ? (0.125f * LOG2E) : 1.0f;
#pragma unroll
            for (int mt = 0; mt < 4; mt++)
#pragma unroll
                for (int r = 0; r < 4; r++) {
                    int m = m0 + wr * 64 + mt * 16 + quad * 4 + r;
                    int bb = m >> 10, ns = m & 1023;
                    size_t idx = (size_t)which * QKV_PART +
                                 (((size_t)(bb * NH + h) * NSEQ + ns) << 6) + d;
                    qkv[idx] = f2bf(acc[mt][nt][r] * sc);
                }
        }
    }
}

// ---------------- proj GEMM: round-9 verbatim (XCD-grouped, WIN) ------------------
#define PBM 64
#define PBN 128
__global__ __launch_bounds__(256, 4) void gemm_proj(const u16* __restrict__ A,
                                                    const u16* __restrict__ Bm,
                                                    float* __restrict__ Co) {
    __shared__ u16 As[PBM * BK];   // 4 KB
    __shared__ u16 Bs[PBN * BK];   // 8 KB
    const int tid = threadIdx.x;
    const int w = tid >> 6, lane = tid & 63, quad = lane >> 4, l16 = lane & 15;
    const int wr = w >> 1, wc = w & 1;   // 2 x 2 wave grid, each 32x64
    const int lin = blockIdx.x + 6 * blockIdx.y;   // 0..767
    const int xcd = lin & 7, j = lin >> 3;         // j in 0..95
    const int yp = xcd * 16 + j / 6;               // m-panel, XCD-contiguous
    const int xp = j % 6;                          // n-panel
    const int m0 = yp * PBM;
    const int n0 = xp * PBN;
    const int K = INNER, N = DIMC;

    const int rl = lane >> 2, cc = lane & 3;
    const int ra = w * 16 + rl;
    const u16* agp = A + (size_t)(m0 + ra) * K + ((cc - ((ra >> 1) & 3)) & 3) * 8;
    const int aslot = (w * 16) * BK;
    const u16* bgp[2]; int bslot[2];
#pragma unroll
    for (int j2 = 0; j2 < 2; j2++) {
        int rb = j2 * 64 + w * 16 + rl;
        bgp[j2] = Bm + (size_t)(n0 + rb) * K + ((cc - ((rb >> 1) & 3)) & 3) * 8;
        bslot[j2] = (j2 * 64 + w * 16) * BK;
    }
    const int swz = ((quad + ((l16 >> 1) & 3)) & 3) * 8;
    int aoff[2], boff[4];
#pragma unroll
    for (int t = 0; t < 2; t++) aoff[t] = (wr * 32 + t * 16 + l16) * BK + swz;
#pragma unroll
    for (int t = 0; t < 4; t++) boff[t] = (wc * 64 + t * 16 + l16) * BK + swz;

    f32x4 acc[2][4] = {};
    const int NIT = K / BK;   // 24
    for (int it = 0; it < NIT; ++it) {
        int kt = it * BK;
        async16(&As[aslot], agp + kt);
        async16(&Bs[bslot[0]], bgp[0] + kt);
        async16(&Bs[bslot[1]], bgp[1] + kt);
        __syncthreads();
        short8 af[2], bf[4];
#pragma unroll
        for (int t = 0; t < 2; t++) af[t] = *(const short8*)(&As[aoff[t]]);
#pragma unroll
        for (int t = 0; t < 4; t++) bf[t] = *(const short8*)(&Bs[boff[t]]);
#pragma unroll
        for (int mt = 0; mt < 2; mt++)
#pragma unroll
            for (int nt = 0; nt < 4; nt++)
                acc[mt][nt] = __builtin_amdgcn_mfma_f32_16x16x32_bf16(af[mt], bf[nt],
                                                                      acc[mt][nt], 0, 0, 0);
        __syncthreads();
    }
#pragma unroll
    for (int mt = 0; mt < 2; mt++)
#pragma unroll
        for (int nt = 0; nt < 4; nt++) {
            int o = n0 + wc * 64 + nt * 16 + l16;
#pragma unroll
            for (int r = 0; r < 4; r++) {
                int m = m0 + wr * 32 + mt * 16 + quad * 4 + r;
                Co[(size_t)m * N + o] = acc[mt][nt][r];
            }
        }
}

// ---------------- Flash attention: staged pipeline + conflict-free V' layout ------
__global__ __launch_bounds__(256) void attn_kernel(const u16* __restrict__ qkv,
                                                   u16* __restrict__ attn) {
    __shared__ u16 Ks[3][64 * 64];   // rows: key pos, cols: d  (rotated 16B chunks)
    __shared__ u16 Vs[3][64 * 64];   // rows: d; slot-swizzled V' tile (linear copy)

    const int tid = threadIdx.x;
    const int w = tid >> 6, lane = tid & 63, quad = lane >> 4, l16 = lane & 15;
    const int bh = blockIdx.x, qt = blockIdx.y;
    const size_t headoff = (size_t)bh * NSEQ * DH;
    const u16* Qp = qkv + headoff;
    const u16* Kp = qkv + QKV_PART + headoff;
    const u16* Vtp = qkv + 2 * QKV_PART + headoff;   // V' tile-blocked layout
    const int q0 = qt * 128 + w * 32;

    const int rl8 = lane >> 3, cc8 = lane & 7;
    const u16* kg[2]; const u16* vg[2]; int ksl[2];
#pragma unroll
    for (int j = 0; j < 2; j++) {
        int r = w * 16 + j * 8 + rl8;
        int c = ((cc8 - r) & 7) * 8;
        kg[j] = Kp + (size_t)r * DH + c;        // K: rotated chunks (unchanged)
        vg[j] = Vtp + (size_t)r * 64 + cc8 * 8; // V': LINEAR (swizzle baked in global)
        ksl[j] = (w * 16 + j * 8) * 64;
    }

    const int sw0 = ((quad + l16) & 7) * 8;
    const int sw1 = ((quad + 4 + l16) & 7) * 8;

    // Q loads FIRST, pinned complete BEFORE any async16 is issued
    short8 qf[2][2];
#pragma unroll
    for (int mf = 0; mf < 2; mf++) {
        qf[mf][0] = *(const short8*)(Qp + (size_t)(q0 + mf * 16 + l16) * DH + quad * 8);
        qf[mf][1] = *(const short8*)(Qp + (size_t)(q0 + mf * 16 + l16) * DH + 32 + quad * 8);
    }
    asm volatile("" :: "v"(qf[0][0]), "v"(qf[0][1]), "v"(qf[1][0]), "v"(qf[1][1]));

    // prefetch tiles 0..2 (4 loads each; V tile stride = 4096 u16 = kt*64)
#pragma unroll
    for (int tt = 0; tt < 3; tt++) {
        int kt = tt * 64;
#pragma unroll
        for (int j = 0; j < 2; j++) {
            async16(&Ks[tt][ksl[j]], kg[j] + (size_t)kt * DH);
            async16(&Vs[tt][ksl[j]], vg[j] + (size_t)kt * 64);
        }
    }

    f32x4 oacc[2][4] = {};          // O^T[d][q]
    float lsum[2] = {0.f, 0.f};

    const int NIT = NSEQ / 64;   // 16
    int cur = 0;
    for (int it = 0; it < NIT; ++it) {
        if (it < NIT - 1) wait_vm<4>();  // tile it landed; tile it+1 in flight
        else              wait_vm<0>();
        block_barrier();
        if (it >= 1 && it < NIT - 2) {
            int pre = cur + 2; if (pre >= 3) pre -= 3;
            int ktn = (it + 2) * 64;
#pragma unroll
            for (int j = 0; j < 2; j++) {
                async16(&Ks[pre][ksl[j]], kg[j] + (size_t)ktn * DH);
                async16(&Vs[pre][ksl[j]], vg[j] + (size_t)ktn * 64);
            }
        }

        short8 kf[4][2];
#pragma unroll
        for (int nt = 0; nt < 4; nt++) {
            const u16* kr = &Ks[cur][(nt * 16 + l16) * 64];
            kf[nt][0] = *(const short8*)(kr + sw0);
            kf[nt][1] = *(const short8*)(kr + sw1);
        }
        // V' read: slot s=(4c+quad+row)&15 -> within each 16-lane phase the 16
        // slots are distinct -> 32 banks covered once -> conflict-free.
        short4v vf[4][4];
#pragma unroll
        for (int nt2 = 0; nt2 < 4; nt2++) {
            int row = nt2 * 16 + l16;
#pragma unroll
            for (int c = 0; c < 4; c++) {
                int off = row * 64 + (((4 * c + quad + row) & 15) << 2);
                vf[nt2][c] = *(const short4v*)(&Vs[cur][off]);
            }
        }

#pragma unroll
        for (int mf = 0; mf < 2; mf++) {
            f32x4 st[4];
#pragma unroll
            for (int nt = 0; nt < 4; nt++) {
                f32x4 z = {};
                z = __builtin_amdgcn_mfma_f32_16x16x32_bf16(kf[nt][0], qf[mf][0], z, 0, 0, 0);
                z = __builtin_amdgcn_mfma_f32_16x16x32_bf16(kf[nt][1], qf[mf][1], z, 0, 0, 0);
                st[nt] = z;
            }
            short4v pf[4];
#pragma unroll
            for (int c = 0; c < 4; c++) {
                float p0 = __builtin_amdgcn_exp2f(st[c][0]);
                float p1 = __builtin_amdgcn_exp2f(st[c][1]);
                float p2 = __builtin_amdgcn_exp2f(st[c][2]);
                float p3 = __builtin_amdgcn_exp2f(st[c][3]);
                lsum[mf] += (p0 + p1) + (p2 + p3);
                uint2 u = {pkbf(p0, p1), pkbf(p2, p3)};
                pf[c] = __builtin_bit_cast(short4v, u);
            }
#pragma unroll
            for (int nt2 = 0; nt2 < 4; nt2++)
#pragma unroll
                for (int c = 0; c < 4; c++)
                    oacc[mf][nt2] = mfma16(vf[nt2][c], pf[c], oacc[mf][nt2]);
        }
        cur = (cur == 2) ? 0 : cur + 1;
    }

#pragma unroll
    for (int mf = 0; mf < 2; mf++) {
        float v = lsum[mf];
        v += __shfl_xor(v, 16);
        v += __shfl_xor(v, 32);
        lsum[mf] = 1.0f / v;
    }

    const int b = bh / NH, h = bh - (bh / NH) * NH;
#pragma unroll
    for (int mf = 0; mf < 2; mf++) {
        int q = q0 + mf * 16 + l16;
        float inv = lsum[mf];
#pragma unroll
        for (int nt2 = 0; nt2 < 4; nt2++) {
            uint2 u = {pkbf(oacc[mf][nt2][0] * inv, oacc[mf][nt2][1] * inv),
                       pkbf(oacc[mf][nt2][2] * inv, oacc[mf][nt2][3] * inv)};
            int d = nt2 * 16 + quad * 4;
            *(uint2*)(attn + ((size_t)(b * NSEQ + q)) * INNER + h * DH + d) = u;
        }
    }
}

extern "C" void kernel_launch(void* const* d_in, const int* in_sizes, int n_in,
                              void* d_out, int out_size, void* d_ws, size_t ws_size,
                              hipStream_t stream) {
    const float* x = (const float*)d_in[0];
    const float* w_qkv = (const float*)d_in[1];
    const float* w_proj = (const float*)d_in[2];
    float* out = (float*)d_out;

    u16* xb = (u16*)d_ws;
    u16* wqkvb = xb + 6291456;
    u16* wprojb = wqkvb + 1769472;
    u16* qkvb = wprojb + 589824;
    u16* attnb = qkvb + 18874368;

    cvt_all<<<NCVT / 256, 256, 0, stream>>>(x, w_qkv, w_proj, xb, wqkvb, wprojb);

    dim3 g1(QKVN / 192, MTOT / 128);   // (12, 64) = 768 blocks = exactly 3/CU
    gemm_qkv<<<g1, 512, 0, stream>>>(xb, wqkvb, qkvb);

    dim3 g2(HEADS_TOT, NSEQ / 128);    // (96, 8) — same-head blocks co-XCD
    attn_kernel<<<g2, 256, 0, stream>>>(qkvb, attnb);

    dim3 g3(INNER / PBN, MTOT / PBM);  // (6, 128), 3 blocks/CU, XCD-grouped in-kernel
    gemm_proj<<<g3, 256, 0, stream>>>(attnb, wprojb, out);
}